// Round 5
// baseline (599.374 us; speedup 1.0000x reference)
//
#include <hip/hip_runtime.h>
#include <stdint.h>

// ---------------------------------------------------------------------------
// Problem constants
// ---------------------------------------------------------------------------
#define NB   7
#define SIN  16
#define DD   128
#define BB   32
#define TT   2048
#define TM   64          // t-rows per block
#define KMAX 31

// LDS strides (elements, ushort/bf16). All multiples of 8 (16B-aligned rows).
#define XWS  40          // x window stride  (95 rows)
#define HS   136         // h / z / m buffers (64 rows)
#define US   264         // u buffer (64 rows)

// ws (bf16 element offsets)
#define O_CWT 0           // [7][128][512]
#define O_W1T 458752      // [7][256][128]
#define O_W2T 688128      // [7][128][256]
#define O_WCT 917504      // [7][128][128]  Wc[n][c][k] = sum_j proj_w[n][k][j]*mix_w1[n*64+j][c]
#define O_M2T 1032192     // [16][128]
#define O_B1A 1034240     // [128] adjusted mix bias (bf16): mix_b1 + proj_b @ mix_w1
#define W_TOTAL 1034368

// prep segment sizes
#define NSEG_CW  444416   // 7*31*16*128  (round-3 bug: was 454272 -> n=7 overflow corrupted w1T)
#define NSEG_PAD 14336    // 7*128*16
#define NSEG_W1  229376   // 7*128*256
#define NSEG_W2  229376
#define NSEG_WC  114688   // 7*128*128
#define NSEG_M2  2048
#define NSEG_B1  128

typedef short v8s __attribute__((ext_vector_type(8)));
typedef float v4f __attribute__((ext_vector_type(4)));

__device__ __forceinline__ unsigned short f2b(float f) {
    unsigned u = __float_as_uint(f);
    u += 0x7fffu + ((u >> 16) & 1u);          // round-to-nearest-even
    return (unsigned short)(u >> 16);
}
__device__ __forceinline__ float b2f(unsigned short h) {
    return __uint_as_float(((unsigned)h) << 16);
}
__device__ __forceinline__ float gelu_fast(float x) {   // sigmoid approx (inner FFN only)
    return x / (1.f + __expf(-1.702f * x));
}
__device__ __forceinline__ float gelu_exact(float x) {  // final mix gelu
    return 0.5f * x * (1.f + erff(x * 0.70710678118654752f));
}

// ---------------------------------------------------------------------------
// Weight prep: fp32 -> bf16, transposed to B-fragment-friendly layouts.
// All READS are lane-coalesced; scattered 2B writes land in L2 (wsb is
// L2-resident and immediately consumed). Wc = proj_w @ mix_w1 folded GEMM.
// ---------------------------------------------------------------------------
__global__ void prep_weights(const float* __restrict__ conv_w,
                             const float* __restrict__ ffn_w1,
                             const float* __restrict__ ffn_w2,
                             const float* __restrict__ proj_w,
                             const float* __restrict__ mix_w1,
                             const float* __restrict__ mix_w2,
                             const float* __restrict__ proj_b,
                             const float* __restrict__ mix_b1,
                             unsigned short* __restrict__ wsb) {
    const int i0 = blockIdx.x * 256 + threadIdx.x;
    const int stride = gridDim.x * 256;

    // cwT[n][d][k*16+s] = conv_w[n][k][s][d]   (read coalesced over d)
    for (int o = i0; o < NSEG_CW; o += stride) {
        int n = o / 63488; int r = o % 63488;
        int k = r >> 11; int s = (r >> 7) & 15; int d = r & 127;
        float v = conv_w[((n * 31 + k) * 16 + s) * 128 + d];
        wsb[(size_t)(n * 128 + d) * 512 + k * 16 + s] = f2b(v);
    }
    // cwT zero pad (k == 31)
    for (int o = i0; o < NSEG_PAD; o += stride) {
        int n = o >> 11; int d = (o >> 4) & 127; int s = o & 15;
        wsb[(size_t)(n * 128 + d) * 512 + 496 + s] = 0;
    }
    // w1T[n][e][k] = ffn_w1[n][k][e]   (read coalesced over e)
    for (int o = i0; o < NSEG_W1; o += stride) {
        int n = o >> 15; int k = (o >> 8) & 127; int e = o & 255;
        float v = ffn_w1[(n * 128 + k) * 256 + e];
        wsb[O_W1T + (size_t)(n * 256 + e) * 128 + k] = f2b(v);
    }
    // w2T[n][d][e] = ffn_w2[n][e][d]   (read coalesced over d)
    for (int o = i0; o < NSEG_W2; o += stride) {
        int n = o >> 15; int e = (o >> 7) & 255; int d = o & 127;
        float v = ffn_w2[(n * 256 + e) * 128 + d];
        wsb[O_W2T + (size_t)(n * 128 + d) * 256 + e] = f2b(v);
    }
    // WcT[n][c][k] = sum_j proj_w[n][k][j] * mix_w1[n*64+j][c]
    // (mix_w1 read coalesced over c; proj_w broadcast per 128-lane group)
    for (int o = i0; o < NSEG_WC; o += stride) {
        int n = o >> 14; int k = (o >> 7) & 127; int c = o & 127;
        const float* pw = proj_w + (size_t)(n * 128 + k) * 64;
        const float* mw = mix_w1 + (size_t)(n * 64) * 128 + c;
        float s = 0.f;
        #pragma unroll 8
        for (int j = 0; j < 64; j++)
            s += pw[j] * mw[(size_t)j * 128];
        wsb[O_WCT + (size_t)(n * 128 + c) * 128 + k] = f2b(s);
    }
    // m2T[o16][c] = mix_w2[c][o16]
    for (int o = i0; o < NSEG_M2; o += stride) {
        int o16 = o >> 7; int c = o & 127;
        wsb[O_M2T + o16 * 128 + c] = f2b(mix_w2[c * 16 + o16]);
    }
    // b1adj[c] = mix_b1[c] + proj_b @ mix_w1   (unrolled for MLP)
    for (int o = i0; o < NSEG_B1; o += stride) {
        float s = mix_b1[o];
        #pragma unroll 8
        for (int kk = 0; kk < 448; kk++)
            s += proj_b[kk] * mix_w1[kk * 128 + o];
        wsb[O_B1A + o] = f2b(s);
    }
}

// ---------------------------------------------------------------------------
// Fused main kernel: one block = 64 t-rows of one batch, full pipeline.
// 512 threads / 8 waves (2M x 4N split per GEMM). Same LDS as the 256-thread
// version -> 2 blocks/CU but 16 waves/CU (4/SIMD) for latency hiding.
// __launch_bounds__(512, 2): VGPR cap >= 128 under either interpretation of
// the 2nd arg (round 1's (512,4) collapsed VGPR to 64 and spilled 28 MB).
// ---------------------------------------------------------------------------
__global__ __launch_bounds__(512, 2)
void fused_main(const float* __restrict__ x,
                const float* __restrict__ conv_b,
                const float* __restrict__ dec_g, const float* __restrict__ dec_b,
                const float* __restrict__ n2_g,  const float* __restrict__ n2_b,
                const float* __restrict__ ffn_b1, const float* __restrict__ ffn_b2,
                const unsigned short* __restrict__ wsb,
                float* __restrict__ out,
                const float* __restrict__ mix_b2) {
    __shared__ __align__(16) unsigned short xw[95 * XWS];    //  7,600 B
    __shared__ __align__(16) unsigned short hbuf[TM * HS];   // 17,408 B
    __shared__ __align__(16) unsigned short zbuf[TM * HS];   // 17,408 B
    __shared__ __align__(16) unsigned short ubuf[TM * US];   // 33,792 B

    const int tid  = threadIdx.x;
    const int lane = tid & 63;
    const int w    = tid >> 6;       // wave 0..7
    const int wm   = w >> 2;         // M-half  0..1 (rows wm*32..wm*32+31)
    const int wn   = w & 3;          // N-quarter 0..3
    const int l16  = lane & 15;
    const int quad = lane >> 4;      // 0..3
    const int bb   = blockIdx.x >> 5;
    const int t0   = (blockIdx.x & 31) * TM;

    const unsigned short* cwT = wsb + O_CWT;
    const unsigned short* w1T = wsb + O_W1T;
    const unsigned short* w2T = wsb + O_W2T;
    const unsigned short* wcT = wsb + O_WCT;
    const unsigned short* m2T = wsb + O_M2T;

    const int rowb = wm * 32;        // wave's M-base for all GEMM sections

    // ---- S0: stage x window (rows t0-15 .. t0+78), bf16 ----
    for (int i = tid; i < 95 * SIN; i += 512) {
        int r = i >> 4, s = i & 15;
        int t = t0 + r - 15;
        float v = (t >= 0 && t < TT) ? x[((long)bb * TT + t) * SIN + s] : 0.f;
        xw[r * XWS + s] = f2b(v);
    }

    v4f macc[2][2];                  // persistent mix1 accumulators
    #pragma unroll
    for (int a = 0; a < 2; a++)
        #pragma unroll
        for (int c = 0; c < 2; c++)
            macc[a][c] = (v4f){0.f, 0.f, 0.f, 0.f};

    __syncthreads();

    // per-band conv K-ranges (32-aligned, covering the non-zero taps)
    static const int lo_tab[NB] = {0, 64, 128, 160, 192, 192, 224};
    static const int hi_tab[NB] = {512, 416, 384, 352, 320, 288, 288};

    for (int n = 0; n < NB; ++n) {
        // ================= S1: conv (im2col GEMM), M=64 K=K~n N=128 =================
        {
            v4f acc[2][2];
            #pragma unroll
            for (int mt = 0; mt < 2; mt++)
                #pragma unroll
                for (int nt = 0; nt < 2; nt++) acc[mt][nt] = (v4f){0.f, 0.f, 0.f, 0.f};
            const int colb = wn * 32;
            const int lo = lo_tab[n], hi = hi_tab[n];
            for (int kf = lo; kf < hi; kf += 32) {
                const int tap  = (kf >> 4) + (quad >> 1);
                const int scol = (quad & 1) * 8;
                v8s a[2], bf[2];
                #pragma unroll
                for (int mt = 0; mt < 2; mt++)
                    a[mt] = *reinterpret_cast<const v8s*>(&xw[(rowb + mt * 16 + l16 + tap) * XWS + scol]);
                #pragma unroll
                for (int nt = 0; nt < 2; nt++)
                    bf[nt] = *reinterpret_cast<const v8s*>(
                        &cwT[(size_t)(n * 128 + colb + nt * 16 + l16) * 512 + kf + quad * 8]);
                #pragma unroll
                for (int mt = 0; mt < 2; mt++)
                    #pragma unroll
                    for (int nt = 0; nt < 2; nt++)
                        acc[mt][nt] = __builtin_amdgcn_mfma_f32_16x16x32_bf16(a[mt], bf[nt], acc[mt][nt], 0, 0, 0);
            }
            #pragma unroll
            for (int nt = 0; nt < 2; nt++) {
                const int col = colb + nt * 16 + l16;
                const float bias = conv_b[n * 128 + col];
                #pragma unroll
                for (int mt = 0; mt < 2; mt++)
                    #pragma unroll
                    for (int r = 0; r < 4; r++)
                        hbuf[(rowb + mt * 16 + quad * 4 + r) * HS + col] = f2b(acc[mt][nt][r] + bias);
            }
        }
        __syncthreads();

        // ================= S2: dual LayerNorm (8 lanes per row, 16 cols each) =================
        {
            const int row = tid >> 3, q = tid & 7;
            float v[16], s1 = 0.f, s2 = 0.f;
            #pragma unroll
            for (int c8 = 0; c8 < 2; c8++) {
                v8s t8 = *reinterpret_cast<const v8s*>(&hbuf[row * HS + q * 16 + c8 * 8]);
                #pragma unroll
                for (int j = 0; j < 8; j++) {
                    float f = b2f((unsigned short)t8[j]);
                    v[c8 * 8 + j] = f; s1 += f; s2 += f * f;
                }
            }
            s1 += __shfl_xor(s1, 1); s2 += __shfl_xor(s2, 1);
            s1 += __shfl_xor(s1, 2); s2 += __shfl_xor(s2, 2);
            s1 += __shfl_xor(s1, 4); s2 += __shfl_xor(s2, 4);
            const float m1 = s1 * (1.f / 128.f);
            const float rs = rsqrtf(s2 * (1.f / 128.f) - m1 * m1 + 1e-5f);
            const float4* dg4 = (const float4*)(dec_g + n * 128);
            const float4* db4 = (const float4*)(dec_b + n * 128);
            float hv[16], t1 = 0.f, t2 = 0.f;
            #pragma unroll
            for (int c4 = 0; c4 < 4; c4++) {
                float4 g4 = dg4[q * 4 + c4], b4 = db4[q * 4 + c4];
                float ga[4] = {g4.x, g4.y, g4.z, g4.w};
                float ba[4] = {b4.x, b4.y, b4.z, b4.w};
                #pragma unroll
                for (int j = 0; j < 4; j++) {
                    float h = (v[c4 * 4 + j] - m1) * rs * ga[j] + ba[j];
                    hv[c4 * 4 + j] = h; t1 += h; t2 += h * h;
                    hbuf[row * HS + q * 16 + c4 * 4 + j] = f2b(h);
                }
            }
            t1 += __shfl_xor(t1, 1); t2 += __shfl_xor(t2, 1);
            t1 += __shfl_xor(t1, 2); t2 += __shfl_xor(t2, 2);
            t1 += __shfl_xor(t1, 4); t2 += __shfl_xor(t2, 4);
            const float m2 = t1 * (1.f / 128.f);
            const float rs2 = rsqrtf(t2 * (1.f / 128.f) - m2 * m2 + 1e-5f);
            const float4* ng4 = (const float4*)(n2_g + n * 128);
            const float4* nb4 = (const float4*)(n2_b + n * 128);
            #pragma unroll
            for (int c4 = 0; c4 < 4; c4++) {
                float4 g4 = ng4[q * 4 + c4], b4 = nb4[q * 4 + c4];
                float ga[4] = {g4.x, g4.y, g4.z, g4.w};
                float ba[4] = {b4.x, b4.y, b4.z, b4.w};
                #pragma unroll
                for (int j = 0; j < 4; j++) {
                    float z = (hv[c4 * 4 + j] - m2) * rs2 * ga[j] + ba[j];
                    zbuf[row * HS + q * 16 + c4 * 4 + j] = f2b(z);
                }
            }
        }
        __syncthreads();

        // ================= S3: FFN1 + gelu, M=64 K=128 N=256 =================
        {
            v4f acc[2][4];
            #pragma unroll
            for (int mt = 0; mt < 2; mt++)
                #pragma unroll
                for (int et = 0; et < 4; et++) acc[mt][et] = (v4f){0.f, 0.f, 0.f, 0.f};
            const int eb = wn * 64;
            #pragma unroll
            for (int kb = 0; kb < 128; kb += 32) {
                v8s a[2], bf[4];
                #pragma unroll
                for (int mt = 0; mt < 2; mt++)
                    a[mt] = *reinterpret_cast<const v8s*>(&zbuf[(rowb + mt * 16 + l16) * HS + kb + quad * 8]);
                #pragma unroll
                for (int et = 0; et < 4; et++)
                    bf[et] = *reinterpret_cast<const v8s*>(
                        &w1T[(size_t)(n * 256 + eb + et * 16 + l16) * 128 + kb + quad * 8]);
                #pragma unroll
                for (int mt = 0; mt < 2; mt++)
                    #pragma unroll
                    for (int et = 0; et < 4; et++)
                        acc[mt][et] = __builtin_amdgcn_mfma_f32_16x16x32_bf16(a[mt], bf[et], acc[mt][et], 0, 0, 0);
            }
            #pragma unroll
            for (int et = 0; et < 4; et++) {
                const int e = eb + et * 16 + l16;
                const float bias = ffn_b1[n * 256 + e];
                #pragma unroll
                for (int mt = 0; mt < 2; mt++)
                    #pragma unroll
                    for (int r = 0; r < 4; r++)
                        ubuf[(rowb + mt * 16 + quad * 4 + r) * US + e] = f2b(gelu_fast(acc[mt][et][r] + bias));
            }
        }
        __syncthreads();

        // ================= S4: FFN2 + residual, M=64 K=256 N=128 =================
        {
            v4f acc[2][2];
            #pragma unroll
            for (int mt = 0; mt < 2; mt++)
                #pragma unroll
                for (int nt = 0; nt < 2; nt++) acc[mt][nt] = (v4f){0.f, 0.f, 0.f, 0.f};
            const int dbs = wn * 32;
            #pragma unroll
            for (int kb = 0; kb < 256; kb += 32) {
                v8s a[2], bf[2];
                #pragma unroll
                for (int mt = 0; mt < 2; mt++)
                    a[mt] = *reinterpret_cast<const v8s*>(&ubuf[(rowb + mt * 16 + l16) * US + kb + quad * 8]);
                #pragma unroll
                for (int nt = 0; nt < 2; nt++)
                    bf[nt] = *reinterpret_cast<const v8s*>(
                        &w2T[(size_t)(n * 128 + dbs + nt * 16 + l16) * 256 + kb + quad * 8]);
                #pragma unroll
                for (int mt = 0; mt < 2; mt++)
                    #pragma unroll
                    for (int nt = 0; nt < 2; nt++)
                        acc[mt][nt] = __builtin_amdgcn_mfma_f32_16x16x32_bf16(a[mt], bf[nt], acc[mt][nt], 0, 0, 0);
            }
            #pragma unroll
            for (int nt = 0; nt < 2; nt++) {
                const int col = dbs + nt * 16 + l16;
                const float bias = ffn_b2[n * 128 + col];
                #pragma unroll
                for (int mt = 0; mt < 2; mt++)
                    #pragma unroll
                    for (int r = 0; r < 4; r++) {
                        const int row = rowb + mt * 16 + quad * 4 + r;
                        float bo = acc[mt][nt][r] + bias + b2f(hbuf[row * HS + col]);
                        zbuf[row * HS + col] = f2b(bo);
                    }
            }
        }
        __syncthreads();

        // ===== S5: fused proj+mix1 partial accumulate, M=64 K=128 N=128 (Wc) =====
        {
            #pragma unroll
            for (int kb = 0; kb < 128; kb += 32) {
                v8s a[2], bf[2];
                #pragma unroll
                for (int mt = 0; mt < 2; mt++)
                    a[mt] = *reinterpret_cast<const v8s*>(&zbuf[(rowb + mt * 16 + l16) * HS + kb + quad * 8]);
                #pragma unroll
                for (int nt = 0; nt < 2; nt++)
                    bf[nt] = *reinterpret_cast<const v8s*>(
                        &wcT[(size_t)(n * 128 + wn * 32 + nt * 16 + l16) * 128 + kb + quad * 8]);
                #pragma unroll
                for (int mt = 0; mt < 2; mt++)
                    #pragma unroll
                    for (int nt = 0; nt < 2; nt++)
                        macc[mt][nt] = __builtin_amdgcn_mfma_f32_16x16x32_bf16(a[mt], bf[nt], macc[mt][nt], 0, 0, 0);
            }
        }
        // no barrier: next S1 writes hbuf (last read before S4's barrier), reads
        // xw/cwT; S5 reads zbuf which S1 doesn't touch; S2's zbuf writes are
        // ordered behind S1's barrier.
    }
    __syncthreads();   // order last band's S5 zbuf reads before S7 zbuf writes

    // ================= S7: m = gelu(macc + b1adj) -> zbuf (bf16) =================
    #pragma unroll
    for (int nt = 0; nt < 2; nt++) {
        const int col = wn * 32 + nt * 16 + l16;
        const float bias = b2f(wsb[O_B1A + col]);
        #pragma unroll
        for (int mt = 0; mt < 2; mt++)
            #pragma unroll
            for (int r = 0; r < 4; r++)
                zbuf[(rowb + mt * 16 + quad * 4 + r) * HS + col] = f2b(gelu_exact(macc[mt][nt][r] + bias));
    }
    __syncthreads();

    // ================= S8: mix2, M=64 K=128 N=16 (waves 0..3 -> rows w*16..) =================
    if (w < 4) {
        v4f acc = (v4f){0.f, 0.f, 0.f, 0.f};
        #pragma unroll
        for (int kb = 0; kb < 128; kb += 32) {
            v8s a  = *reinterpret_cast<const v8s*>(&zbuf[(w * 16 + l16) * HS + kb + quad * 8]);
            v8s bf = *reinterpret_cast<const v8s*>(&m2T[(size_t)l16 * 128 + kb + quad * 8]);
            acc = __builtin_amdgcn_mfma_f32_16x16x32_bf16(a, bf, acc, 0, 0, 0);
        }
        const float bias = mix_b2[l16];
        #pragma unroll
        for (int r = 0; r < 4; r++) {
            const int row = w * 16 + quad * 4 + r;
            out[((long)bb * TT + t0 + row) * SIN + l16] = acc[r] + bias;
        }
    }
}

// ---------------------------------------------------------------------------
extern "C" void kernel_launch(void* const* d_in, const int* in_sizes, int n_in,
                              void* d_out, int out_size, void* d_ws, size_t ws_size,
                              hipStream_t stream) {
    (void)in_sizes; (void)n_in; (void)out_size; (void)ws_size;
    const float* x      = (const float*)d_in[0];
    const float* conv_w = (const float*)d_in[1];
    const float* conv_b = (const float*)d_in[2];
    const float* dec_g  = (const float*)d_in[3];
    const float* dec_b  = (const float*)d_in[4];
    const float* n2_g   = (const float*)d_in[5];
    const float* n2_b   = (const float*)d_in[6];
    const float* ffn_w1 = (const float*)d_in[7];
    const float* ffn_b1 = (const float*)d_in[8];
    const float* ffn_w2 = (const float*)d_in[9];
    const float* ffn_b2 = (const float*)d_in[10];
    const float* proj_w = (const float*)d_in[11];
    const float* proj_b = (const float*)d_in[12];
    const float* mix_w1 = (const float*)d_in[13];
    const float* mix_b1 = (const float*)d_in[14];
    const float* mix_w2 = (const float*)d_in[15];
    const float* mix_b2 = (const float*)d_in[16];
    unsigned short* wsb = (unsigned short*)d_ws;
    float* out = (float*)d_out;

    hipLaunchKernelGGL(prep_weights, dim3(512), dim3(256), 0, stream,
                       conv_w, ffn_w1, ffn_w2, proj_w, mix_w1, mix_w2,
                       proj_b, mix_b1, wsb);
    hipLaunchKernelGGL(fused_main, dim3(BB * (TT / TM)), dim3(512), 0, stream,
                       x, conv_b, dec_g, dec_b, n2_g, n2_b, ffn_b1, ffn_b2,
                       wsb, out, mix_b2);
}

// Round 6
// 537.595 us; speedup vs baseline: 1.1149x; 1.1149x over previous
//
#include <hip/hip_runtime.h>
#include <stdint.h>

// ---------------------------------------------------------------------------
// Problem constants
// ---------------------------------------------------------------------------
#define NB   7
#define SIN  16
#define DD   128
#define BB   32
#define TT   2048
#define TM   32          // t-rows per block (halved: 4 blocks/CU in LDS)
#define KMAX 31
#define XROWS (TM + 31)  // x window rows = 63

// LDS strides (elements, ushort/bf16). All multiples of 8 (16B-aligned rows).
#define XWS  40          // x window stride  (63 rows)
#define HS   136         // h / z buffers (32 rows)
#define US   264         // u buffer (32 rows)

// ws (bf16 element offsets)
#define O_CWT 0           // [7][128][512]
#define O_W1T 458752      // [7][256][128]
#define O_W2T 688128      // [7][128][256]
#define O_WCT 917504      // [7][128][128]  Wc[n][c][k] = sum_j proj_w[n][k][j]*mix_w1[n*64+j][c]
#define O_M2T 1032192     // [16][128]
#define O_B1A 1034240     // [128] adjusted mix bias (bf16): mix_b1 + proj_b @ mix_w1
#define W_TOTAL 1034368

// prep segment sizes
#define NSEG_CW  444416   // 7*31*16*128
#define NSEG_PAD 14336    // 7*128*16
#define NSEG_W1  229376   // 7*128*256
#define NSEG_W2  229376
#define NSEG_WC  114688   // 7*128*128
#define NSEG_M2  2048
#define NSEG_B1  128

typedef short v8s __attribute__((ext_vector_type(8)));
typedef float v4f __attribute__((ext_vector_type(4)));

__device__ __forceinline__ unsigned short f2b(float f) {
    unsigned u = __float_as_uint(f);
    u += 0x7fffu + ((u >> 16) & 1u);          // round-to-nearest-even
    return (unsigned short)(u >> 16);
}
__device__ __forceinline__ float b2f(unsigned short h) {
    return __uint_as_float(((unsigned)h) << 16);
}
__device__ __forceinline__ float gelu_fast(float x) {   // sigmoid approx (inner FFN only)
    return x / (1.f + __expf(-1.702f * x));
}
__device__ __forceinline__ float gelu_exact(float x) {  // final mix gelu
    return 0.5f * x * (1.f + erff(x * 0.70710678118654752f));
}

// ---------------------------------------------------------------------------
// Weight prep: fp32 -> bf16, transposed to B-fragment-friendly layouts.
// (verified passing in round 5)
// ---------------------------------------------------------------------------
__global__ void prep_weights(const float* __restrict__ conv_w,
                             const float* __restrict__ ffn_w1,
                             const float* __restrict__ ffn_w2,
                             const float* __restrict__ proj_w,
                             const float* __restrict__ mix_w1,
                             const float* __restrict__ mix_w2,
                             const float* __restrict__ proj_b,
                             const float* __restrict__ mix_b1,
                             unsigned short* __restrict__ wsb) {
    const int i0 = blockIdx.x * 256 + threadIdx.x;
    const int stride = gridDim.x * 256;

    // cwT[n][d][k*16+s] = conv_w[n][k][s][d]   (read coalesced over d)
    for (int o = i0; o < NSEG_CW; o += stride) {
        int n = o / 63488; int r = o % 63488;
        int k = r >> 11; int s = (r >> 7) & 15; int d = r & 127;
        float v = conv_w[((n * 31 + k) * 16 + s) * 128 + d];
        wsb[(size_t)(n * 128 + d) * 512 + k * 16 + s] = f2b(v);
    }
    // cwT zero pad (k == 31)
    for (int o = i0; o < NSEG_PAD; o += stride) {
        int n = o >> 11; int d = (o >> 4) & 127; int s = o & 15;
        wsb[(size_t)(n * 128 + d) * 512 + 496 + s] = 0;
    }
    // w1T[n][e][k] = ffn_w1[n][k][e]   (read coalesced over e)
    for (int o = i0; o < NSEG_W1; o += stride) {
        int n = o >> 15; int k = (o >> 8) & 127; int e = o & 255;
        float v = ffn_w1[(n * 128 + k) * 256 + e];
        wsb[O_W1T + (size_t)(n * 256 + e) * 128 + k] = f2b(v);
    }
    // w2T[n][d][e] = ffn_w2[n][e][d]   (read coalesced over d)
    for (int o = i0; o < NSEG_W2; o += stride) {
        int n = o >> 15; int e = (o >> 7) & 255; int d = o & 127;
        float v = ffn_w2[(n * 256 + e) * 128 + d];
        wsb[O_W2T + (size_t)(n * 128 + d) * 256 + e] = f2b(v);
    }
    // WcT[n][c][k] = sum_j proj_w[n][k][j] * mix_w1[n*64+j][c]
    for (int o = i0; o < NSEG_WC; o += stride) {
        int n = o >> 14; int k = (o >> 7) & 127; int c = o & 127;
        const float* pw = proj_w + (size_t)(n * 128 + k) * 64;
        const float* mw = mix_w1 + (size_t)(n * 64) * 128 + c;
        float s = 0.f;
        #pragma unroll 8
        for (int j = 0; j < 64; j++)
            s += pw[j] * mw[(size_t)j * 128];
        wsb[O_WCT + (size_t)(n * 128 + c) * 128 + k] = f2b(s);
    }
    // m2T[o16][c] = mix_w2[c][o16]
    for (int o = i0; o < NSEG_M2; o += stride) {
        int o16 = o >> 7; int c = o & 127;
        wsb[O_M2T + o16 * 128 + c] = f2b(mix_w2[c * 16 + o16]);
    }
    // b1adj[c] = mix_b1[c] + proj_b @ mix_w1
    for (int o = i0; o < NSEG_B1; o += stride) {
        float s = mix_b1[o];
        #pragma unroll 8
        for (int kk = 0; kk < 448; kk++)
            s += proj_b[kk] * mix_w1[kk * 128 + o];
        wsb[O_B1A + o] = f2b(s);
    }
}

// ---------------------------------------------------------------------------
// Fused main kernel: one block = 32 t-rows of one batch, full pipeline.
// 256 threads / 4 waves, wave w owns output cols w*32..w*32+31 (2 mt tiles).
// LDS 39.3 KB -> 4 blocks/CU fit in LDS; occupancy now limited only by
// VGPR+AGPR total (unified file; steps at 64/128/256 per wave).
// ---------------------------------------------------------------------------
__global__ __launch_bounds__(256)
void fused_main(const float* __restrict__ x,
                const float* __restrict__ conv_b,
                const float* __restrict__ dec_g, const float* __restrict__ dec_b,
                const float* __restrict__ n2_g,  const float* __restrict__ n2_b,
                const float* __restrict__ ffn_b1, const float* __restrict__ ffn_b2,
                const unsigned short* __restrict__ wsb,
                float* __restrict__ out,
                const float* __restrict__ mix_b2) {
    __shared__ __align__(16) unsigned short xw[XROWS * XWS]; //  5,040 B
    __shared__ __align__(16) unsigned short hbuf[TM * HS];   //  8,704 B
    __shared__ __align__(16) unsigned short zbuf[TM * HS];   //  8,704 B
    __shared__ __align__(16) unsigned short ubuf[TM * US];   // 16,896 B

    const int tid  = threadIdx.x;
    const int lane = tid & 63;
    const int w    = tid >> 6;       // wave 0..3
    const int l16  = lane & 15;
    const int quad = lane >> 4;      // 0..3
    const int bb   = blockIdx.x >> 6;          // TT/TM = 64 tiles per batch
    const int t0   = (blockIdx.x & 63) * TM;

    const unsigned short* cwT = wsb + O_CWT;
    const unsigned short* w1T = wsb + O_W1T;
    const unsigned short* w2T = wsb + O_W2T;
    const unsigned short* wcT = wsb + O_WCT;
    const unsigned short* m2T = wsb + O_M2T;

    // ---- S0: stage x window (rows t0-15 .. t0+47), bf16 ----
    for (int i = tid; i < XROWS * SIN; i += 256) {
        int r = i >> 4, s = i & 15;
        int t = t0 + r - 15;
        float v = (t >= 0 && t < TT) ? x[((long)bb * TT + t) * SIN + s] : 0.f;
        xw[r * XWS + s] = f2b(v);
    }

    v4f macc[2][2];                  // persistent mix1 accumulators (cols w*32..w*32+31)
    #pragma unroll
    for (int a = 0; a < 2; a++)
        #pragma unroll
        for (int c = 0; c < 2; c++)
            macc[a][c] = (v4f){0.f, 0.f, 0.f, 0.f};

    __syncthreads();

    // per-band conv K-ranges (32-aligned, covering the non-zero taps)
    static const int lo_tab[NB] = {0, 64, 128, 160, 192, 192, 224};
    static const int hi_tab[NB] = {512, 416, 384, 352, 320, 288, 288};

    for (int n = 0; n < NB; ++n) {
        // ================= S1: conv (im2col GEMM), M=32 K=K~n N=128 =================
        {
            v4f acc[2][2];
            #pragma unroll
            for (int mt = 0; mt < 2; mt++)
                #pragma unroll
                for (int nt = 0; nt < 2; nt++) acc[mt][nt] = (v4f){0.f, 0.f, 0.f, 0.f};
            const int colb = w * 32;
            const int lo = lo_tab[n], hi = hi_tab[n];
            for (int kf = lo; kf < hi; kf += 32) {
                const int tap  = (kf >> 4) + (quad >> 1);
                const int scol = (quad & 1) * 8;
                v8s a[2], bf[2];
                #pragma unroll
                for (int mt = 0; mt < 2; mt++)
                    a[mt] = *reinterpret_cast<const v8s*>(&xw[(mt * 16 + l16 + tap) * XWS + scol]);
                #pragma unroll
                for (int nt = 0; nt < 2; nt++)
                    bf[nt] = *reinterpret_cast<const v8s*>(
                        &cwT[(size_t)(n * 128 + colb + nt * 16 + l16) * 512 + kf + quad * 8]);
                #pragma unroll
                for (int mt = 0; mt < 2; mt++)
                    #pragma unroll
                    for (int nt = 0; nt < 2; nt++)
                        acc[mt][nt] = __builtin_amdgcn_mfma_f32_16x16x32_bf16(a[mt], bf[nt], acc[mt][nt], 0, 0, 0);
            }
            #pragma unroll
            for (int nt = 0; nt < 2; nt++) {
                const int col = colb + nt * 16 + l16;
                const float bias = conv_b[n * 128 + col];
                #pragma unroll
                for (int mt = 0; mt < 2; mt++)
                    #pragma unroll
                    for (int r = 0; r < 4; r++)
                        hbuf[(mt * 16 + quad * 4 + r) * HS + col] = f2b(acc[mt][nt][r] + bias);
            }
        }
        __syncthreads();

        // ================= S2: dual LayerNorm (8 lanes per row, 16 cols each) =================
        {
            const int row = tid >> 3, q = tid & 7;      // 32 rows x 8 lanes
            float v[16], s1 = 0.f, s2 = 0.f;
            #pragma unroll
            for (int c8 = 0; c8 < 2; c8++) {
                v8s t8 = *reinterpret_cast<const v8s*>(&hbuf[row * HS + q * 16 + c8 * 8]);
                #pragma unroll
                for (int j = 0; j < 8; j++) {
                    float f = b2f((unsigned short)t8[j]);
                    v[c8 * 8 + j] = f; s1 += f; s2 += f * f;
                }
            }
            s1 += __shfl_xor(s1, 1); s2 += __shfl_xor(s2, 1);
            s1 += __shfl_xor(s1, 2); s2 += __shfl_xor(s2, 2);
            s1 += __shfl_xor(s1, 4); s2 += __shfl_xor(s2, 4);
            const float m1 = s1 * (1.f / 128.f);
            const float rs = rsqrtf(s2 * (1.f / 128.f) - m1 * m1 + 1e-5f);
            const float4* dg4 = (const float4*)(dec_g + n * 128);
            const float4* db4 = (const float4*)(dec_b + n * 128);
            float hv[16], t1 = 0.f, t2 = 0.f;
            #pragma unroll
            for (int c4 = 0; c4 < 4; c4++) {
                float4 g4 = dg4[q * 4 + c4], b4 = db4[q * 4 + c4];
                float ga[4] = {g4.x, g4.y, g4.z, g4.w};
                float ba[4] = {b4.x, b4.y, b4.z, b4.w};
                #pragma unroll
                for (int j = 0; j < 4; j++) {
                    float h = (v[c4 * 4 + j] - m1) * rs * ga[j] + ba[j];
                    hv[c4 * 4 + j] = h; t1 += h; t2 += h * h;
                    hbuf[row * HS + q * 16 + c4 * 4 + j] = f2b(h);
                }
            }
            t1 += __shfl_xor(t1, 1); t2 += __shfl_xor(t2, 1);
            t1 += __shfl_xor(t1, 2); t2 += __shfl_xor(t2, 2);
            t1 += __shfl_xor(t1, 4); t2 += __shfl_xor(t2, 4);
            const float m2 = t1 * (1.f / 128.f);
            const float rs2 = rsqrtf(t2 * (1.f / 128.f) - m2 * m2 + 1e-5f);
            const float4* ng4 = (const float4*)(n2_g + n * 128);
            const float4* nb4 = (const float4*)(n2_b + n * 128);
            #pragma unroll
            for (int c4 = 0; c4 < 4; c4++) {
                float4 g4 = ng4[q * 4 + c4], b4 = nb4[q * 4 + c4];
                float ga[4] = {g4.x, g4.y, g4.z, g4.w};
                float ba[4] = {b4.x, b4.y, b4.z, b4.w};
                #pragma unroll
                for (int j = 0; j < 4; j++) {
                    float z = (hv[c4 * 4 + j] - m2) * rs2 * ga[j] + ba[j];
                    zbuf[row * HS + q * 16 + c4 * 4 + j] = f2b(z);
                }
            }
        }
        __syncthreads();

        // ================= S3: FFN1 + gelu, M=32 K=128 N=256 =================
        {
            v4f acc[2][4];
            #pragma unroll
            for (int mt = 0; mt < 2; mt++)
                #pragma unroll
                for (int et = 0; et < 4; et++) acc[mt][et] = (v4f){0.f, 0.f, 0.f, 0.f};
            const int eb = w * 64;
            #pragma unroll
            for (int kb = 0; kb < 128; kb += 32) {
                v8s a[2], bf[4];
                #pragma unroll
                for (int mt = 0; mt < 2; mt++)
                    a[mt] = *reinterpret_cast<const v8s*>(&zbuf[(mt * 16 + l16) * HS + kb + quad * 8]);
                #pragma unroll
                for (int et = 0; et < 4; et++)
                    bf[et] = *reinterpret_cast<const v8s*>(
                        &w1T[(size_t)(n * 256 + eb + et * 16 + l16) * 128 + kb + quad * 8]);
                #pragma unroll
                for (int mt = 0; mt < 2; mt++)
                    #pragma unroll
                    for (int et = 0; et < 4; et++)
                        acc[mt][et] = __builtin_amdgcn_mfma_f32_16x16x32_bf16(a[mt], bf[et], acc[mt][et], 0, 0, 0);
            }
            #pragma unroll
            for (int et = 0; et < 4; et++) {
                const int e = eb + et * 16 + l16;
                const float bias = ffn_b1[n * 256 + e];
                #pragma unroll
                for (int mt = 0; mt < 2; mt++)
                    #pragma unroll
                    for (int r = 0; r < 4; r++)
                        ubuf[(mt * 16 + quad * 4 + r) * US + e] = f2b(gelu_fast(acc[mt][et][r] + bias));
            }
        }
        __syncthreads();

        // ================= S4: FFN2 + residual, M=32 K=256 N=128 =================
        {
            v4f acc[2][2];
            #pragma unroll
            for (int mt = 0; mt < 2; mt++)
                #pragma unroll
                for (int nt = 0; nt < 2; nt++) acc[mt][nt] = (v4f){0.f, 0.f, 0.f, 0.f};
            const int dbs = w * 32;
            #pragma unroll
            for (int kb = 0; kb < 256; kb += 32) {
                v8s a[2], bf[2];
                #pragma unroll
                for (int mt = 0; mt < 2; mt++)
                    a[mt] = *reinterpret_cast<const v8s*>(&ubuf[(mt * 16 + l16) * US + kb + quad * 8]);
                #pragma unroll
                for (int nt = 0; nt < 2; nt++)
                    bf[nt] = *reinterpret_cast<const v8s*>(
                        &w2T[(size_t)(n * 128 + dbs + nt * 16 + l16) * 256 + kb + quad * 8]);
                #pragma unroll
                for (int mt = 0; mt < 2; mt++)
                    #pragma unroll
                    for (int nt = 0; nt < 2; nt++)
                        acc[mt][nt] = __builtin_amdgcn_mfma_f32_16x16x32_bf16(a[mt], bf[nt], acc[mt][nt], 0, 0, 0);
            }
            #pragma unroll
            for (int nt = 0; nt < 2; nt++) {
                const int col = dbs + nt * 16 + l16;
                const float bias = ffn_b2[n * 128 + col];
                #pragma unroll
                for (int mt = 0; mt < 2; mt++)
                    #pragma unroll
                    for (int r = 0; r < 4; r++) {
                        const int row = mt * 16 + quad * 4 + r;
                        float bo = acc[mt][nt][r] + bias + b2f(hbuf[row * HS + col]);
                        zbuf[row * HS + col] = f2b(bo);
                    }
            }
        }
        __syncthreads();

        // ===== S5: fused proj+mix1 partial accumulate, M=32 K=128 N=128 (Wc) =====
        {
            #pragma unroll
            for (int kb = 0; kb < 128; kb += 32) {
                v8s a[2], bf[2];
                #pragma unroll
                for (int mt = 0; mt < 2; mt++)
                    a[mt] = *reinterpret_cast<const v8s*>(&zbuf[(mt * 16 + l16) * HS + kb + quad * 8]);
                #pragma unroll
                for (int nt = 0; nt < 2; nt++)
                    bf[nt] = *reinterpret_cast<const v8s*>(
                        &wcT[(size_t)(n * 128 + w * 32 + nt * 16 + l16) * 128 + kb + quad * 8]);
                #pragma unroll
                for (int mt = 0; mt < 2; mt++)
                    #pragma unroll
                    for (int nt = 0; nt < 2; nt++)
                        macc[mt][nt] = __builtin_amdgcn_mfma_f32_16x16x32_bf16(a[mt], bf[nt], macc[mt][nt], 0, 0, 0);
            }
        }
        // no barrier: next S1 writes hbuf (last read before S4's barrier), reads
        // xw/cwT; S5 reads zbuf which S1 doesn't touch; S2's zbuf writes are
        // ordered behind S1's barrier.
    }
    __syncthreads();   // order last band's S5 zbuf reads before S7 zbuf writes

    // ================= S7: m = gelu(macc + b1adj) -> zbuf (bf16) =================
    #pragma unroll
    for (int nt = 0; nt < 2; nt++) {
        const int col = w * 32 + nt * 16 + l16;
        const float bias = b2f(wsb[O_B1A + col]);
        #pragma unroll
        for (int mt = 0; mt < 2; mt++)
            #pragma unroll
            for (int r = 0; r < 4; r++)
                zbuf[(mt * 16 + quad * 4 + r) * HS + col] = f2b(gelu_exact(macc[mt][nt][r] + bias));
    }
    __syncthreads();

    // ================= S8: mix2, M=32 K=128 N=16 (waves 0..1 -> rows w*16..) =================
    if (w < 2) {
        v4f acc = (v4f){0.f, 0.f, 0.f, 0.f};
        #pragma unroll
        for (int kb = 0; kb < 128; kb += 32) {
            v8s a  = *reinterpret_cast<const v8s*>(&zbuf[(w * 16 + l16) * HS + kb + quad * 8]);
            v8s bf = *reinterpret_cast<const v8s*>(&m2T[(size_t)l16 * 128 + kb + quad * 8]);
            acc = __builtin_amdgcn_mfma_f32_16x16x32_bf16(a, bf, acc, 0, 0, 0);
        }
        const float bias = mix_b2[l16];
        #pragma unroll
        for (int r = 0; r < 4; r++) {
            const int row = w * 16 + quad * 4 + r;
            out[((long)bb * TT + t0 + row) * SIN + l16] = acc[r] + bias;
        }
    }
}

// ---------------------------------------------------------------------------
extern "C" void kernel_launch(void* const* d_in, const int* in_sizes, int n_in,
                              void* d_out, int out_size, void* d_ws, size_t ws_size,
                              hipStream_t stream) {
    (void)in_sizes; (void)n_in; (void)out_size; (void)ws_size;
    const float* x      = (const float*)d_in[0];
    const float* conv_w = (const float*)d_in[1];
    const float* conv_b = (const float*)d_in[2];
    const float* dec_g  = (const float*)d_in[3];
    const float* dec_b  = (const float*)d_in[4];
    const float* n2_g   = (const float*)d_in[5];
    const float* n2_b   = (const float*)d_in[6];
    const float* ffn_w1 = (const float*)d_in[7];
    const float* ffn_b1 = (const float*)d_in[8];
    const float* ffn_w2 = (const float*)d_in[9];
    const float* ffn_b2 = (const float*)d_in[10];
    const float* proj_w = (const float*)d_in[11];
    const float* proj_b = (const float*)d_in[12];
    const float* mix_w1 = (const float*)d_in[13];
    const float* mix_b1 = (const float*)d_in[14];
    const float* mix_w2 = (const float*)d_in[15];
    const float* mix_b2 = (const float*)d_in[16];
    unsigned short* wsb = (unsigned short*)d_ws;
    float* out = (float*)d_out;

    hipLaunchKernelGGL(prep_weights, dim3(512), dim3(256), 0, stream,
                       conv_w, ffn_w1, ffn_w2, proj_w, mix_w1, mix_w2,
                       proj_b, mix_b1, wsb);
    hipLaunchKernelGGL(fused_main, dim3(BB * (TT / TM)), dim3(256), 0, stream,
                       x, conv_b, dec_g, dec_b, n2_g, n2_b, ffn_b1, ffn_b2,
                       wsb, out, mix_b2);
}

// Round 8
// 516.525 us; speedup vs baseline: 1.1604x; 1.0408x over previous
//
#include <hip/hip_runtime.h>
#include <stdint.h>

// ---------------------------------------------------------------------------
// Problem constants
// ---------------------------------------------------------------------------
#define NB   7
#define SIN  16
#define DD   128
#define BB   32
#define TT   2048
#define TM   32          // t-rows per block (LDS 39.4 KB -> 4 blocks/CU)
#define KMAX 31
#define XROWS (TM + 31)  // x window rows = 63

// LDS strides (elements, ushort/bf16). All multiples of 8 (16B-aligned rows).
#define XWS  40          // x window stride  (63 rows)
#define HS   136         // h / z buffers (32 rows)
#define US   264         // u buffer (32 rows)

// ws (bf16 element offsets)
#define O_CWT 0           // [7][128][512]
#define O_W1T 458752      // [7][256][128]
#define O_W2T 688128      // [7][128][256]
#define O_WCT 917504      // [7][128][128]  Wc[n][c][k] = sum_j proj_w[n][k][j]*mix_w1[n*64+j][c]
#define O_M2T 1032192     // [16][128]
#define O_B1A 1034240     // [128] adjusted mix bias: mix_b1 + proj_b @ mix_w1
#define W_TOTAL 1034368

// prep segment sizes
#define NSEG_CW  444416   // 7*31*16*128
#define NSEG_PAD 14336    // 7*128*16
#define NSEG_W1  229376   // 7*128*256
#define NSEG_W2  229376
#define NSEG_WC  114688   // 7*128*128
#define NSEG_M2  2048
#define NSEG_B1  128

typedef short v8s __attribute__((ext_vector_type(8)));
typedef float v4f __attribute__((ext_vector_type(4)));

__device__ __forceinline__ unsigned short f2b(float f) {
    unsigned u = __float_as_uint(f);
    u += 0x7fffu + ((u >> 16) & 1u);          // round-to-nearest-even
    return (unsigned short)(u >> 16);
}
__device__ __forceinline__ float b2f(unsigned short h) {
    return __uint_as_float(((unsigned)h) << 16);
}
// pack two f32 -> one u32 of 2x bf16 (RNE), single instruction on gfx950
__device__ __forceinline__ unsigned cvt_pk_bf16(float lo, float hi) {
    unsigned r;
    asm volatile("v_cvt_pk_bf16_f32 %0, %1, %2" : "=v"(r) : "v"(lo), "v"(hi));
    return r;
}
__device__ __forceinline__ float gelu_fast(float x) {   // sigmoid approx (inner FFN only)
    return x / (1.f + __expf(-1.702f * x));
}
__device__ __forceinline__ float gelu_exact(float x) {  // final mix gelu
    return 0.5f * x * (1.f + erff(x * 0.70710678118654752f));
}

// ---------------------------------------------------------------------------
// Weight prep (verified passing in rounds 5/6) — unchanged.
// ---------------------------------------------------------------------------
__global__ void prep_weights(const float* __restrict__ conv_w,
                             const float* __restrict__ ffn_w1,
                             const float* __restrict__ ffn_w2,
                             const float* __restrict__ proj_w,
                             const float* __restrict__ mix_w1,
                             const float* __restrict__ mix_w2,
                             const float* __restrict__ proj_b,
                             const float* __restrict__ mix_b1,
                             unsigned short* __restrict__ wsb) {
    const int i0 = blockIdx.x * 256 + threadIdx.x;
    const int stride = gridDim.x * 256;

    for (int o = i0; o < NSEG_CW; o += stride) {
        int n = o / 63488; int r = o % 63488;
        int k = r >> 11; int s = (r >> 7) & 15; int d = r & 127;
        float v = conv_w[((n * 31 + k) * 16 + s) * 128 + d];
        wsb[(size_t)(n * 128 + d) * 512 + k * 16 + s] = f2b(v);
    }
    for (int o = i0; o < NSEG_PAD; o += stride) {
        int n = o >> 11; int d = (o >> 4) & 127; int s = o & 15;
        wsb[(size_t)(n * 128 + d) * 512 + 496 + s] = 0;
    }
    for (int o = i0; o < NSEG_W1; o += stride) {
        int n = o >> 15; int k = (o >> 8) & 127; int e = o & 255;
        float v = ffn_w1[(n * 128 + k) * 256 + e];
        wsb[O_W1T + (size_t)(n * 256 + e) * 128 + k] = f2b(v);
    }
    for (int o = i0; o < NSEG_W2; o += stride) {
        int n = o >> 15; int e = (o >> 7) & 255; int d = o & 127;
        float v = ffn_w2[(n * 256 + e) * 128 + d];
        wsb[O_W2T + (size_t)(n * 128 + d) * 256 + e] = f2b(v);
    }
    for (int o = i0; o < NSEG_WC; o += stride) {
        int n = o >> 14; int k = (o >> 7) & 127; int c = o & 127;
        const float* pw = proj_w + (size_t)(n * 128 + k) * 64;
        const float* mw = mix_w1 + (size_t)(n * 64) * 128 + c;
        float s = 0.f;
        #pragma unroll 8
        for (int j = 0; j < 64; j++)
            s += pw[j] * mw[(size_t)j * 128];
        wsb[O_WCT + (size_t)(n * 128 + c) * 128 + k] = f2b(s);
    }
    for (int o = i0; o < NSEG_M2; o += stride) {
        int o16 = o >> 7; int c = o & 127;
        wsb[O_M2T + o16 * 128 + c] = f2b(mix_w2[c * 16 + o16]);
    }
    for (int o = i0; o < NSEG_B1; o += stride) {
        float s = mix_b1[o];
        #pragma unroll 8
        for (int kk = 0; kk < 448; kk++)
            s += proj_b[kk] * mix_w1[kk * 128 + o];
        wsb[O_B1A + o] = f2b(s);
    }
}

// ---------------------------------------------------------------------------
// Fused main kernel: one block = 32 t-rows, 256 threads / 4 waves.
// LDS 39.4 KB (4 blocks/CU). __launch_bounds__(256,4) pins total regs <=128
// per wave (register quantum 64: waves/SIMD = 512/quantized-total, so <=128
// total -> 4 waves/SIMD -> 16 waves/CU). S2 is streaming/in-place (~20 live
// regs); epilogues use v_cvt_pk_bf16_f32 packed conversion.
// ---------------------------------------------------------------------------
__global__ __launch_bounds__(256, 4)
void fused_main(const float* __restrict__ x,
                const float* __restrict__ conv_b,
                const float* __restrict__ dec_g, const float* __restrict__ dec_b,
                const float* __restrict__ n2_g,  const float* __restrict__ n2_b,
                const float* __restrict__ ffn_b1, const float* __restrict__ ffn_b2,
                const unsigned short* __restrict__ wsb,
                float* __restrict__ out,
                const float* __restrict__ mix_b2) {
    __shared__ __align__(16) unsigned short xw[XROWS * XWS]; //  5,040 B
    __shared__ __align__(16) unsigned short hbuf[TM * HS];   //  8,704 B
    __shared__ __align__(16) unsigned short zbuf[TM * HS];   //  8,704 B
    __shared__ __align__(16) unsigned short ubuf[TM * US];   // 16,896 B

    const int tid  = threadIdx.x;
    const int lane = tid & 63;
    const int w    = tid >> 6;       // wave 0..3
    const int l16  = lane & 15;
    const int quad = lane >> 4;      // 0..3
    const int bb   = blockIdx.x >> 6;          // TT/TM = 64 tiles per batch
    const int t0   = (blockIdx.x & 63) * TM;

    const unsigned short* cwT = wsb + O_CWT;
    const unsigned short* w1T = wsb + O_W1T;
    const unsigned short* w2T = wsb + O_W2T;
    const unsigned short* wcT = wsb + O_WCT;
    const unsigned short* m2T = wsb + O_M2T;

    // ---- S0: stage x window (rows t0-15 .. t0+47), bf16 ----
    for (int i = tid; i < XROWS * SIN; i += 256) {
        int r = i >> 4, s = i & 15;
        int t = t0 + r - 15;
        float v = (t >= 0 && t < TT) ? x[((long)bb * TT + t) * SIN + s] : 0.f;
        xw[r * XWS + s] = f2b(v);
    }

    v4f macc[2][2];                  // persistent mix1 accumulators (cols w*32..w*32+31)
    #pragma unroll
    for (int a = 0; a < 2; a++)
        #pragma unroll
        for (int c = 0; c < 2; c++)
            macc[a][c] = (v4f){0.f, 0.f, 0.f, 0.f};

    __syncthreads();

    // per-band conv K-ranges (32-aligned, covering the non-zero taps)
    static const int lo_tab[NB] = {0, 64, 128, 160, 192, 192, 224};
    static const int hi_tab[NB] = {512, 416, 384, 352, 320, 288, 288};

    for (int n = 0; n < NB; ++n) {
        // ================= S1: conv (im2col GEMM), M=32 K=K~n N=128 =================
        {
            v4f acc[2][2];
            #pragma unroll
            for (int mt = 0; mt < 2; mt++)
                #pragma unroll
                for (int nt = 0; nt < 2; nt++) acc[mt][nt] = (v4f){0.f, 0.f, 0.f, 0.f};
            const int colb = w * 32;
            const int lo = lo_tab[n], hi = hi_tab[n];
            for (int kf = lo; kf < hi; kf += 32) {
                const int tap  = (kf >> 4) + (quad >> 1);
                const int scol = (quad & 1) * 8;
                v8s a[2], bf[2];
                #pragma unroll
                for (int mt = 0; mt < 2; mt++)
                    a[mt] = *reinterpret_cast<const v8s*>(&xw[(mt * 16 + l16 + tap) * XWS + scol]);
                #pragma unroll
                for (int nt = 0; nt < 2; nt++)
                    bf[nt] = *reinterpret_cast<const v8s*>(
                        &cwT[(size_t)(n * 128 + colb + nt * 16 + l16) * 512 + kf + quad * 8]);
                #pragma unroll
                for (int mt = 0; mt < 2; mt++)
                    #pragma unroll
                    for (int nt = 0; nt < 2; nt++)
                        acc[mt][nt] = __builtin_amdgcn_mfma_f32_16x16x32_bf16(a[mt], bf[nt], acc[mt][nt], 0, 0, 0);
            }
            #pragma unroll
            for (int nt = 0; nt < 2; nt++) {
                const int col = colb + nt * 16 + l16;
                const float bias = conv_b[n * 128 + col];
                #pragma unroll
                for (int mt = 0; mt < 2; mt++) {
                    unsigned p01 = cvt_pk_bf16(acc[mt][nt][0] + bias, acc[mt][nt][1] + bias);
                    unsigned p23 = cvt_pk_bf16(acc[mt][nt][2] + bias, acc[mt][nt][3] + bias);
                    const int r0 = (mt * 16 + quad * 4) * HS + col;
                    hbuf[r0]          = (unsigned short)p01;
                    hbuf[r0 + HS]     = (unsigned short)(p01 >> 16);
                    hbuf[r0 + 2 * HS] = (unsigned short)p23;
                    hbuf[r0 + 3 * HS] = (unsigned short)(p23 >> 16);
                }
            }
        }
        __syncthreads();

        // ======= S2: dual LayerNorm, streaming/in-place (8 lanes/row, 16 cols) =======
        {
            const int row = tid >> 3, q = tid & 7;
            const int base = row * HS + q * 16;
            v8s t8a = *reinterpret_cast<const v8s*>(&hbuf[base]);
            v8s t8b = *reinterpret_cast<const v8s*>(&hbuf[base + 8]);
            float s1 = 0.f, s2 = 0.f;
            #pragma unroll
            for (int j = 0; j < 8; j++) {
                float f = b2f((unsigned short)t8a[j]); s1 += f; s2 = fmaf(f, f, s2);
                float g = b2f((unsigned short)t8b[j]); s1 += g; s2 = fmaf(g, g, s2);
            }
            s1 += __shfl_xor(s1, 1); s2 += __shfl_xor(s2, 1);
            s1 += __shfl_xor(s1, 2); s2 += __shfl_xor(s2, 2);
            s1 += __shfl_xor(s1, 4); s2 += __shfl_xor(s2, 4);
            const float m1 = s1 * (1.f / 128.f);
            const float rs = rsqrtf(s2 * (1.f / 128.f) - m1 * m1 + 1e-5f);
            const float m1rs = m1 * rs;
            const float4* dg4 = (const float4*)(dec_g + n * 128) + q * 4;
            const float4* db4 = (const float4*)(dec_b + n * 128) + q * 4;
            float t1 = 0.f, t2 = 0.f;
            unsigned hw[8];
            #pragma unroll
            for (int c4 = 0; c4 < 4; c4++) {
                float4 g4 = dg4[c4], b4 = db4[c4];
                float v0, v1, v2, v3;
                if (c4 < 2) {
                    v0 = b2f((unsigned short)t8a[c4 * 4 + 0]); v1 = b2f((unsigned short)t8a[c4 * 4 + 1]);
                    v2 = b2f((unsigned short)t8a[c4 * 4 + 2]); v3 = b2f((unsigned short)t8a[c4 * 4 + 3]);
                } else {
                    v0 = b2f((unsigned short)t8b[(c4 - 2) * 4 + 0]); v1 = b2f((unsigned short)t8b[(c4 - 2) * 4 + 1]);
                    v2 = b2f((unsigned short)t8b[(c4 - 2) * 4 + 2]); v3 = b2f((unsigned short)t8b[(c4 - 2) * 4 + 3]);
                }
                float h0 = fmaf(fmaf(v0, rs, -m1rs), g4.x, b4.x);
                float h1 = fmaf(fmaf(v1, rs, -m1rs), g4.y, b4.y);
                float h2 = fmaf(fmaf(v2, rs, -m1rs), g4.z, b4.z);
                float h3 = fmaf(fmaf(v3, rs, -m1rs), g4.w, b4.w);
                t1 += h0 + h1 + h2 + h3;
                t2 = fmaf(h0, h0, t2); t2 = fmaf(h1, h1, t2);
                t2 = fmaf(h2, h2, t2); t2 = fmaf(h3, h3, t2);
                unsigned w01 = cvt_pk_bf16(h0, h1);
                unsigned w23 = cvt_pk_bf16(h2, h3);
                hw[c4 * 2] = w01; hw[c4 * 2 + 1] = w23;
                *reinterpret_cast<unsigned*>(&hbuf[base + c4 * 4])     = w01;
                *reinterpret_cast<unsigned*>(&hbuf[base + c4 * 4 + 2]) = w23;
            }
            t1 += __shfl_xor(t1, 1); t2 += __shfl_xor(t2, 1);
            t1 += __shfl_xor(t1, 2); t2 += __shfl_xor(t2, 2);
            t1 += __shfl_xor(t1, 4); t2 += __shfl_xor(t2, 4);
            const float m2 = t1 * (1.f / 128.f);
            const float rs2 = rsqrtf(t2 * (1.f / 128.f) - m2 * m2 + 1e-5f);
            const float m2rs2 = m2 * rs2;
            const float4* ng4 = (const float4*)(n2_g + n * 128) + q * 4;
            const float4* nb4 = (const float4*)(n2_b + n * 128) + q * 4;
            const int zbase = row * HS + q * 16;
            #pragma unroll
            for (int c4 = 0; c4 < 4; c4++) {
                float4 g4 = ng4[c4], b4 = nb4[c4];
                unsigned w01 = hw[c4 * 2], w23 = hw[c4 * 2 + 1];
                float h0 = __uint_as_float(w01 << 16);
                float h1 = __uint_as_float(w01 & 0xffff0000u);
                float h2 = __uint_as_float(w23 << 16);
                float h3 = __uint_as_float(w23 & 0xffff0000u);
                float z0 = fmaf(fmaf(h0, rs2, -m2rs2), g4.x, b4.x);
                float z1 = fmaf(fmaf(h1, rs2, -m2rs2), g4.y, b4.y);
                float z2 = fmaf(fmaf(h2, rs2, -m2rs2), g4.z, b4.z);
                float z3 = fmaf(fmaf(h3, rs2, -m2rs2), g4.w, b4.w);
                *reinterpret_cast<unsigned*>(&zbuf[zbase + c4 * 4])     = cvt_pk_bf16(z0, z1);
                *reinterpret_cast<unsigned*>(&zbuf[zbase + c4 * 4 + 2]) = cvt_pk_bf16(z2, z3);
            }
        }
        __syncthreads();

        // ================= S3: FFN1 + gelu, M=32 K=128 N=256 =================
        {
            v4f acc[2][4];
            #pragma unroll
            for (int mt = 0; mt < 2; mt++)
                #pragma unroll
                for (int et = 0; et < 4; et++) acc[mt][et] = (v4f){0.f, 0.f, 0.f, 0.f};
            const int eb = w * 64;
            #pragma unroll
            for (int kb = 0; kb < 128; kb += 32) {
                v8s a[2], bf[4];
                #pragma unroll
                for (int mt = 0; mt < 2; mt++)
                    a[mt] = *reinterpret_cast<const v8s*>(&zbuf[(mt * 16 + l16) * HS + kb + quad * 8]);
                #pragma unroll
                for (int et = 0; et < 4; et++)
                    bf[et] = *reinterpret_cast<const v8s*>(
                        &w1T[(size_t)(n * 256 + eb + et * 16 + l16) * 128 + kb + quad * 8]);
                #pragma unroll
                for (int mt = 0; mt < 2; mt++)
                    #pragma unroll
                    for (int et = 0; et < 4; et++)
                        acc[mt][et] = __builtin_amdgcn_mfma_f32_16x16x32_bf16(a[mt], bf[et], acc[mt][et], 0, 0, 0);
            }
            #pragma unroll
            for (int et = 0; et < 4; et++) {
                const int e = eb + et * 16 + l16;
                const float bias = ffn_b1[n * 256 + e];
                #pragma unroll
                for (int mt = 0; mt < 2; mt++) {
                    float g0 = gelu_fast(acc[mt][et][0] + bias);
                    float g1 = gelu_fast(acc[mt][et][1] + bias);
                    float g2 = gelu_fast(acc[mt][et][2] + bias);
                    float g3 = gelu_fast(acc[mt][et][3] + bias);
                    unsigned p01 = cvt_pk_bf16(g0, g1);
                    unsigned p23 = cvt_pk_bf16(g2, g3);
                    const int r0 = (mt * 16 + quad * 4) * US + e;
                    ubuf[r0]          = (unsigned short)p01;
                    ubuf[r0 + US]     = (unsigned short)(p01 >> 16);
                    ubuf[r0 + 2 * US] = (unsigned short)p23;
                    ubuf[r0 + 3 * US] = (unsigned short)(p23 >> 16);
                }
            }
        }
        __syncthreads();

        // ================= S4: FFN2 + residual, M=32 K=256 N=128 =================
        {
            v4f acc[2][2];
            #pragma unroll
            for (int mt = 0; mt < 2; mt++)
                #pragma unroll
                for (int nt = 0; nt < 2; nt++) acc[mt][nt] = (v4f){0.f, 0.f, 0.f, 0.f};
            const int dbs = w * 32;
            #pragma unroll
            for (int kb = 0; kb < 256; kb += 32) {
                v8s a[2], bf[2];
                #pragma unroll
                for (int mt = 0; mt < 2; mt++)
                    a[mt] = *reinterpret_cast<const v8s*>(&ubuf[(mt * 16 + l16) * US + kb + quad * 8]);
                #pragma unroll
                for (int nt = 0; nt < 2; nt++)
                    bf[nt] = *reinterpret_cast<const v8s*>(
                        &w2T[(size_t)(n * 128 + dbs + nt * 16 + l16) * 256 + kb + quad * 8]);
                #pragma unroll
                for (int mt = 0; mt < 2; mt++)
                    #pragma unroll
                    for (int nt = 0; nt < 2; nt++)
                        acc[mt][nt] = __builtin_amdgcn_mfma_f32_16x16x32_bf16(a[mt], bf[nt], acc[mt][nt], 0, 0, 0);
            }
            #pragma unroll
            for (int nt = 0; nt < 2; nt++) {
                const int col = dbs + nt * 16 + l16;
                const float bias = ffn_b2[n * 128 + col];
                #pragma unroll
                for (int mt = 0; mt < 2; mt++) {
                    const int r0 = (mt * 16 + quad * 4) * HS + col;
                    float b0 = acc[mt][nt][0] + bias + b2f(hbuf[r0]);
                    float b1 = acc[mt][nt][1] + bias + b2f(hbuf[r0 + HS]);
                    float b2v = acc[mt][nt][2] + bias + b2f(hbuf[r0 + 2 * HS]);
                    float b3 = acc[mt][nt][3] + bias + b2f(hbuf[r0 + 3 * HS]);
                    unsigned p01 = cvt_pk_bf16(b0, b1);
                    unsigned p23 = cvt_pk_bf16(b2v, b3);
                    zbuf[r0]          = (unsigned short)p01;
                    zbuf[r0 + HS]     = (unsigned short)(p01 >> 16);
                    zbuf[r0 + 2 * HS] = (unsigned short)p23;
                    zbuf[r0 + 3 * HS] = (unsigned short)(p23 >> 16);
                }
            }
        }
        __syncthreads();

        // ===== S5: fused proj+mix1 partial accumulate, M=32 K=128 N=128 (Wc) =====
        {
            #pragma unroll
            for (int kb = 0; kb < 128; kb += 32) {
                v8s a[2], bf[2];
                #pragma unroll
                for (int mt = 0; mt < 2; mt++)
                    a[mt] = *reinterpret_cast<const v8s*>(&zbuf[(mt * 16 + l16) * HS + kb + quad * 8]);
                #pragma unroll
                for (int nt = 0; nt < 2; nt++)
                    bf[nt] = *reinterpret_cast<const v8s*>(
                        &wcT[(size_t)(n * 128 + w * 32 + nt * 16 + l16) * 128 + kb + quad * 8]);
                #pragma unroll
                for (int mt = 0; mt < 2; mt++)
                    #pragma unroll
                    for (int nt = 0; nt < 2; nt++)
                        macc[mt][nt] = __builtin_amdgcn_mfma_f32_16x16x32_bf16(a[mt], bf[nt], macc[mt][nt], 0, 0, 0);
            }
        }
        // no barrier: next S1 writes hbuf (last read before S4's barrier), reads
        // xw/cwT; S5 reads zbuf which S1 doesn't touch; S2's zbuf writes are
        // ordered behind S1's barrier.
    }
    __syncthreads();   // order last band's S5 zbuf reads before S7 zbuf writes

    // ================= S7: m = gelu(macc + b1adj) -> zbuf (bf16) =================
    #pragma unroll
    for (int nt = 0; nt < 2; nt++) {
        const int col = w * 32 + nt * 16 + l16;
        const float bias = b2f(wsb[O_B1A + col]);
        #pragma unroll
        for (int mt = 0; mt < 2; mt++) {
            float g0 = gelu_exact(macc[mt][nt][0] + bias);
            float g1 = gelu_exact(macc[mt][nt][1] + bias);
            float g2 = gelu_exact(macc[mt][nt][2] + bias);
            float g3 = gelu_exact(macc[mt][nt][3] + bias);
            unsigned p01 = cvt_pk_bf16(g0, g1);
            unsigned p23 = cvt_pk_bf16(g2, g3);
            const int r0 = (mt * 16 + quad * 4) * HS + col;
            zbuf[r0]          = (unsigned short)p01;
            zbuf[r0 + HS]     = (unsigned short)(p01 >> 16);
            zbuf[r0 + 2 * HS] = (unsigned short)p23;
            zbuf[r0 + 3 * HS] = (unsigned short)(p23 >> 16);
        }
    }
    __syncthreads();

    // ================= S8: mix2, M=32 K=128 N=16 (waves 0..1 -> rows w*16..) =================
    if (w < 2) {
        v4f acc = (v4f){0.f, 0.f, 0.f, 0.f};
        #pragma unroll
        for (int kb = 0; kb < 128; kb += 32) {
            v8s a  = *reinterpret_cast<const v8s*>(&zbuf[(w * 16 + l16) * HS + kb + quad * 8]);
            v8s bf = *reinterpret_cast<const v8s*>(&m2T[(size_t)l16 * 128 + kb + quad * 8]);
            acc = __builtin_amdgcn_mfma_f32_16x16x32_bf16(a, bf, acc, 0, 0, 0);
        }
        const float bias = mix_b2[l16];
        #pragma unroll
        for (int r = 0; r < 4; r++) {
            const int row = w * 16 + quad * 4 + r;
            out[((long)bb * TT + t0 + row) * SIN + l16] = acc[r] + bias;
        }
    }
}

// ---------------------------------------------------------------------------
extern "C" void kernel_launch(void* const* d_in, const int* in_sizes, int n_in,
                              void* d_out, int out_size, void* d_ws, size_t ws_size,
                              hipStream_t stream) {
    (void)in_sizes; (void)n_in; (void)out_size; (void)ws_size;
    const float* x      = (const float*)d_in[0];
    const float* conv_w = (const float*)d_in[1];
    const float* conv_b = (const float*)d_in[2];
    const float* dec_g  = (const float*)d_in[3];
    const float* dec_b  = (const float*)d_in[4];
    const float* n2_g   = (const float*)d_in[5];
    const float* n2_b   = (const float*)d_in[6];
    const float* ffn_w1 = (const float*)d_in[7];
    const float* ffn_b1 = (const float*)d_in[8];
    const float* ffn_w2 = (const float*)d_in[9];
    const float* ffn_b2 = (const float*)d_in[10];
    const float* proj_w = (const float*)d_in[11];
    const float* proj_b = (const float*)d_in[12];
    const float* mix_w1 = (const float*)d_in[13];
    const float* mix_b1 = (const float*)d_in[14];
    const float* mix_w2 = (const float*)d_in[15];
    const float* mix_b2 = (const float*)d_in[16];
    unsigned short* wsb = (unsigned short*)d_ws;
    float* out = (float*)d_out;

    hipLaunchKernelGGL(prep_weights, dim3(512), dim3(256), 0, stream,
                       conv_w, ffn_w1, ffn_w2, proj_w, mix_w1, mix_w2,
                       proj_b, mix_b1, wsb);
    hipLaunchKernelGGL(fused_main, dim3(BB * (TT / TM)), dim3(256), 0, stream,
                       x, conv_b, dec_g, dec_b, n2_g, n2_b, ffn_b1, ffn_b2,
                       wsb, out, mix_b2);
}

// Round 9
// 447.944 us; speedup vs baseline: 1.3381x; 1.1531x over previous
//
#include <hip/hip_runtime.h>
#include <stdint.h>

// ---------------------------------------------------------------------------
// Problem constants
// ---------------------------------------------------------------------------
#define NB   7
#define SIN  16
#define DD   128
#define BB   32
#define TT   2048
#define TM   64          // t-rows per block
#define KMAX 31

// LDS strides (elements, ushort/bf16). All multiples of 8 (16B-aligned rows).
#define XWS  40          // x window stride  (95 rows)
#define HS   136         // h / z buffers (64 rows)
#define US   264         // u buffer (64 rows)

// ws (bf16 element offsets)
#define O_CWT 0           // [7][128][512]
#define O_W1T 458752      // [7][256][128]
#define O_WFT 688128      // [7][128][256]  Wf[n][c][e] = sum_d ffn_w2[n][e][d]*Wc[n][d][c]
#define O_WCT 917504      // [7][128][128]  Wc[n][c][k] = sum_j proj_w[n][k][j]*mix_w1[n*64+j][c]
#define O_M2T 1032192     // [16][128]
#define O_B1A 1034240     // [128] b1adj = mix_b1 + proj_b@mix_w1 + sum_n ffn_b2[n]@Wc[n]
#define W_TOTAL 1034368

// prep segment sizes
#define NSEG_CW  444416   // 7*31*16*128
#define NSEG_PAD 14336    // 7*128*16
#define NSEG_W1  229376   // 7*128*256
#define NSEG_WC  114688   // 7*128*128
#define NSEG_M2  2048
#define NSEG_WF  229376   // 7*256*128

typedef short v8s __attribute__((ext_vector_type(8)));
typedef float v4f __attribute__((ext_vector_type(4)));

__device__ __forceinline__ unsigned short f2b(float f) {
    unsigned u = __float_as_uint(f);
    u += 0x7fffu + ((u >> 16) & 1u);          // round-to-nearest-even
    return (unsigned short)(u >> 16);
}
__device__ __forceinline__ float b2f(unsigned short h) {
    return __uint_as_float(((unsigned)h) << 16);
}
__device__ __forceinline__ float gelu_fast(float x) {   // sigmoid approx (inner FFN only)
    return x / (1.f + __expf(-1.702f * x));
}
__device__ __forceinline__ float gelu_exact(float x) {  // final mix gelu
    return 0.5f * x * (1.f + erff(x * 0.70710678118654752f));
}

// ---------------------------------------------------------------------------
// prep 1: fp32 -> bf16 transposed layouts + Wc = proj_w @ mix_w1.
// (w2T staging and b1adj moved out; Wf/b1adj computed by prep_wf below.)
// ---------------------------------------------------------------------------
__global__ void prep_weights(const float* __restrict__ conv_w,
                             const float* __restrict__ ffn_w1,
                             const float* __restrict__ proj_w,
                             const float* __restrict__ mix_w1,
                             const float* __restrict__ mix_w2,
                             unsigned short* __restrict__ wsb) {
    const int i0 = blockIdx.x * 256 + threadIdx.x;
    const int stride = gridDim.x * 256;

    // cwT[n][d][k*16+s] = conv_w[n][k][s][d]   (read coalesced over d)
    for (int o = i0; o < NSEG_CW; o += stride) {
        int n = o / 63488; int r = o % 63488;
        int k = r >> 11; int s = (r >> 7) & 15; int d = r & 127;
        float v = conv_w[((n * 31 + k) * 16 + s) * 128 + d];
        wsb[(size_t)(n * 128 + d) * 512 + k * 16 + s] = f2b(v);
    }
    // cwT zero pad (k == 31)
    for (int o = i0; o < NSEG_PAD; o += stride) {
        int n = o >> 11; int d = (o >> 4) & 127; int s = o & 15;
        wsb[(size_t)(n * 128 + d) * 512 + 496 + s] = 0;
    }
    // w1T[n][e][k] = ffn_w1[n][k][e]   (read coalesced over e)
    for (int o = i0; o < NSEG_W1; o += stride) {
        int n = o >> 15; int k = (o >> 8) & 127; int e = o & 255;
        float v = ffn_w1[(n * 128 + k) * 256 + e];
        wsb[O_W1T + (size_t)(n * 256 + e) * 128 + k] = f2b(v);
    }
    // WcT[n][c][k] = sum_j proj_w[n][k][j] * mix_w1[n*64+j][c]
    for (int o = i0; o < NSEG_WC; o += stride) {
        int n = o >> 14; int k = (o >> 7) & 127; int c = o & 127;
        const float* pw = proj_w + (size_t)(n * 128 + k) * 64;
        const float* mw = mix_w1 + (size_t)(n * 64) * 128 + c;
        float s = 0.f;
        #pragma unroll 8
        for (int j = 0; j < 64; j++)
            s += pw[j] * mw[(size_t)j * 128];
        wsb[O_WCT + (size_t)(n * 128 + c) * 128 + k] = f2b(s);
    }
    // m2T[o16][c] = mix_w2[c][o16]
    for (int o = i0; o < NSEG_M2; o += stride) {
        int o16 = o >> 7; int c = o & 127;
        wsb[O_M2T + o16 * 128 + c] = f2b(mix_w2[c * 16 + o16]);
    }
}

// ---------------------------------------------------------------------------
// prep 2 (runs after prep_weights; same stream => ordered):
//   WfT[n][c][e] = sum_d ffn_w2[n][e][d] * Wc[n][d][c]     (reads WcT bf16)
//   b1adj[c] = mix_b1[c] + proj_b@mix_w1 + sum_n ffn_b2[n]@Wc[n]
// ---------------------------------------------------------------------------
__global__ void prep_wf(const float* __restrict__ ffn_w2,
                        const float* __restrict__ ffn_b2,
                        const float* __restrict__ proj_b,
                        const float* __restrict__ mix_w1,
                        const float* __restrict__ mix_b1,
                        unsigned short* __restrict__ wsb) {
    const int i0 = blockIdx.x * 256 + threadIdx.x;
    const int stride = gridDim.x * 256;

    // c inner so the f32 ffn_w2 row is wave-broadcast; WcT rows are per-lane
    // but bf16 and L2-resident (just written by prep_weights).
    for (int o = i0; o < NSEG_WF; o += stride) {
        int n = o >> 15; int r = o & 32767;
        int e = r >> 7; int c = r & 127;
        const float* w2 = ffn_w2 + (size_t)(n * 256 + e) * 128;         // [d]
        const unsigned short* wc = wsb + O_WCT + (size_t)(n * 128 + c) * 128; // [d]
        float s = 0.f;
        #pragma unroll 8
        for (int d = 0; d < 128; d++)
            s += w2[d] * b2f(wc[d]);
        wsb[O_WFT + (size_t)(n * 128 + c) * 256 + e] = f2b(s);
    }
    for (int o = i0; o < 128; o += stride) {
        float s = mix_b1[o];
        #pragma unroll 8
        for (int kk = 0; kk < 448; kk++)
            s += proj_b[kk] * mix_w1[kk * 128 + o];
        for (int n = 0; n < NB; n++) {
            const unsigned short* wc = wsb + O_WCT + (size_t)(n * 128 + o) * 128;
            const float* fb = ffn_b2 + n * 128;
            #pragma unroll 8
            for (int d = 0; d < 128; d++)
                s += fb[d] * b2f(wc[d]);
        }
        wsb[O_B1A + o] = f2b(s);
    }
}

// ---------------------------------------------------------------------------
// Fused main kernel: one block = 64 t-rows, 256 threads / 4 waves.
// S4 (FFN2+residual) eliminated algebraically:
//   macc += band_out @ Wc  ==  h @ Wc  +  u @ (W2 @ Wc)
// so each band is 3 barrier-phases: {conv} {LN} {FFN1 + h@Wc} then u@Wf
// accumulates with no trailing barrier. Same MFMA count as before, minus
// one barrier, minus S4's epilogue VALU and the band_out LDS round-trip.
// ---------------------------------------------------------------------------
__global__ __launch_bounds__(256, 2)
void fused_main(const float* __restrict__ x,
                const float* __restrict__ conv_b,
                const float* __restrict__ dec_g, const float* __restrict__ dec_b,
                const float* __restrict__ n2_g,  const float* __restrict__ n2_b,
                const float* __restrict__ ffn_b1,
                const unsigned short* __restrict__ wsb,
                float* __restrict__ out,
                const float* __restrict__ mix_b2) {
    __shared__ __align__(16) unsigned short xw[95 * XWS];    //  7,600 B
    __shared__ __align__(16) unsigned short hbuf[TM * HS];   // 17,408 B
    __shared__ __align__(16) unsigned short zbuf[TM * HS];   // 17,408 B
    __shared__ __align__(16) unsigned short ubuf[TM * US];   // 33,792 B

    const int tid  = threadIdx.x;
    const int lane = tid & 63;
    const int w    = tid >> 6;       // wave 0..3
    const int l16  = lane & 15;
    const int quad = lane >> 4;      // 0..3
    const int bb   = blockIdx.x >> 5;
    const int t0   = (blockIdx.x & 31) * TM;

    const unsigned short* cwT = wsb + O_CWT;
    const unsigned short* w1T = wsb + O_W1T;
    const unsigned short* wfT = wsb + O_WFT;
    const unsigned short* wcT = wsb + O_WCT;
    const unsigned short* m2T = wsb + O_M2T;

    // ---- S0: stage x window (rows t0-15 .. t0+78), bf16 ----
    for (int i = tid; i < 95 * SIN; i += 256) {
        int r = i >> 4, s = i & 15;
        int t = t0 + r - 15;
        float v = (t >= 0 && t < TT) ? x[((long)bb * TT + t) * SIN + s] : 0.f;
        xw[r * XWS + s] = f2b(v);
    }

    v4f macc[4][2];                  // persistent mix accumulators (cols w*32..w*32+31)
    #pragma unroll
    for (int a = 0; a < 4; a++)
        #pragma unroll
        for (int c = 0; c < 2; c++)
            macc[a][c] = (v4f){0.f, 0.f, 0.f, 0.f};

    __syncthreads();

    // per-band conv K-ranges (32-aligned, covering the non-zero taps)
    static const int lo_tab[NB] = {0, 64, 128, 160, 192, 192, 224};
    static const int hi_tab[NB] = {512, 416, 384, 352, 320, 288, 288};

    for (int n = 0; n < NB; ++n) {
        // ================= S1: conv (im2col GEMM), M=64 K=K~n N=128 =================
        {
            v4f acc[4][2];
            #pragma unroll
            for (int mt = 0; mt < 4; mt++)
                #pragma unroll
                for (int nt = 0; nt < 2; nt++) acc[mt][nt] = (v4f){0.f, 0.f, 0.f, 0.f};
            const int colb = w * 32;
            const int lo = lo_tab[n], hi = hi_tab[n];
            for (int kf = lo; kf < hi; kf += 32) {
                const int tap  = (kf >> 4) + (quad >> 1);
                const int scol = (quad & 1) * 8;
                v8s a[4], bf[2];
                #pragma unroll
                for (int mt = 0; mt < 4; mt++)
                    a[mt] = *reinterpret_cast<const v8s*>(&xw[(mt * 16 + l16 + tap) * XWS + scol]);
                #pragma unroll
                for (int nt = 0; nt < 2; nt++)
                    bf[nt] = *reinterpret_cast<const v8s*>(
                        &cwT[(size_t)(n * 128 + colb + nt * 16 + l16) * 512 + kf + quad * 8]);
                #pragma unroll
                for (int mt = 0; mt < 4; mt++)
                    #pragma unroll
                    for (int nt = 0; nt < 2; nt++)
                        acc[mt][nt] = __builtin_amdgcn_mfma_f32_16x16x32_bf16(a[mt], bf[nt], acc[mt][nt], 0, 0, 0);
            }
            #pragma unroll
            for (int nt = 0; nt < 2; nt++) {
                const int col = colb + nt * 16 + l16;
                const float bias = conv_b[n * 128 + col];
                #pragma unroll
                for (int mt = 0; mt < 4; mt++)
                    #pragma unroll
                    for (int r = 0; r < 4; r++)
                        hbuf[(mt * 16 + quad * 4 + r) * HS + col] = f2b(acc[mt][nt][r] + bias);
            }
        }
        __syncthreads();

        // ================= S2: dual LayerNorm (4 lanes per row) =================
        {
            const int row = tid >> 2, q = tid & 3;
            float v[32], s1 = 0.f, s2 = 0.f;
            #pragma unroll
            for (int c8 = 0; c8 < 4; c8++) {
                v8s t8 = *reinterpret_cast<const v8s*>(&hbuf[row * HS + q * 32 + c8 * 8]);
                #pragma unroll
                for (int j = 0; j < 8; j++) {
                    float f = b2f((unsigned short)t8[j]);
                    v[c8 * 8 + j] = f; s1 += f; s2 += f * f;
                }
            }
            s1 += __shfl_xor(s1, 1); s2 += __shfl_xor(s2, 1);
            s1 += __shfl_xor(s1, 2); s2 += __shfl_xor(s2, 2);
            const float m1 = s1 * (1.f / 128.f);
            const float rs = rsqrtf(s2 * (1.f / 128.f) - m1 * m1 + 1e-5f);
            const float4* dg4 = (const float4*)(dec_g + n * 128);
            const float4* db4 = (const float4*)(dec_b + n * 128);
            float hv[32], t1 = 0.f, t2 = 0.f;
            #pragma unroll
            for (int c4 = 0; c4 < 8; c4++) {
                float4 g4 = dg4[q * 8 + c4], b4 = db4[q * 8 + c4];
                float ga[4] = {g4.x, g4.y, g4.z, g4.w};
                float ba[4] = {b4.x, b4.y, b4.z, b4.w};
                #pragma unroll
                for (int j = 0; j < 4; j++) {
                    float h = (v[c4 * 4 + j] - m1) * rs * ga[j] + ba[j];
                    hv[c4 * 4 + j] = h; t1 += h; t2 += h * h;
                    hbuf[row * HS + q * 32 + c4 * 4 + j] = f2b(h);
                }
            }
            t1 += __shfl_xor(t1, 1); t2 += __shfl_xor(t2, 1);
            t1 += __shfl_xor(t1, 2); t2 += __shfl_xor(t2, 2);
            const float m2 = t1 * (1.f / 128.f);
            const float rs2 = rsqrtf(t2 * (1.f / 128.f) - m2 * m2 + 1e-5f);
            const float4* ng4 = (const float4*)(n2_g + n * 128);
            const float4* nb4 = (const float4*)(n2_b + n * 128);
            #pragma unroll
            for (int c4 = 0; c4 < 8; c4++) {
                float4 g4 = ng4[q * 8 + c4], b4 = nb4[q * 8 + c4];
                float ga[4] = {g4.x, g4.y, g4.z, g4.w};
                float ba[4] = {b4.x, b4.y, b4.z, b4.w};
                #pragma unroll
                for (int j = 0; j < 4; j++) {
                    float z = (hv[c4 * 4 + j] - m2) * rs2 * ga[j] + ba[j];
                    zbuf[row * HS + q * 32 + c4 * 4 + j] = f2b(z);
                }
            }
        }
        __syncthreads();

        // ========== S3: FFN1 + gelu (zbuf -> ubuf)  +  S5b: macc += h @ Wc ==========
        {
            v4f acc[4][4];
            #pragma unroll
            for (int mt = 0; mt < 4; mt++)
                #pragma unroll
                for (int et = 0; et < 4; et++) acc[mt][et] = (v4f){0.f, 0.f, 0.f, 0.f};
            const int eb = w * 64;
            #pragma unroll
            for (int kb = 0; kb < 128; kb += 32) {
                v8s a[4], bf[4];
                #pragma unroll
                for (int mt = 0; mt < 4; mt++)
                    a[mt] = *reinterpret_cast<const v8s*>(&zbuf[(mt * 16 + l16) * HS + kb + quad * 8]);
                #pragma unroll
                for (int et = 0; et < 4; et++)
                    bf[et] = *reinterpret_cast<const v8s*>(
                        &w1T[(size_t)(n * 256 + eb + et * 16 + l16) * 128 + kb + quad * 8]);
                #pragma unroll
                for (int mt = 0; mt < 4; mt++)
                    #pragma unroll
                    for (int et = 0; et < 4; et++)
                        acc[mt][et] = __builtin_amdgcn_mfma_f32_16x16x32_bf16(a[mt], bf[et], acc[mt][et], 0, 0, 0);
            }
            #pragma unroll
            for (int et = 0; et < 4; et++) {
                const int e = eb + et * 16 + l16;
                const float bias = ffn_b1[n * 256 + e];
                #pragma unroll
                for (int mt = 0; mt < 4; mt++)
                    #pragma unroll
                    for (int r = 0; r < 4; r++)
                        ubuf[(mt * 16 + quad * 4 + r) * US + e] = f2b(gelu_fast(acc[mt][et][r] + bias));
            }
            // S5b: macc += h @ Wc   (hbuf is final LN1 output; zbuf/ubuf untouched)
            #pragma unroll
            for (int kb = 0; kb < 128; kb += 32) {
                v8s a[4], bf[2];
                #pragma unroll
                for (int mt = 0; mt < 4; mt++)
                    a[mt] = *reinterpret_cast<const v8s*>(&hbuf[(mt * 16 + l16) * HS + kb + quad * 8]);
                #pragma unroll
                for (int nt = 0; nt < 2; nt++)
                    bf[nt] = *reinterpret_cast<const v8s*>(
                        &wcT[(size_t)(n * 128 + w * 32 + nt * 16 + l16) * 128 + kb + quad * 8]);
                #pragma unroll
                for (int mt = 0; mt < 4; mt++)
                    #pragma unroll
                    for (int nt = 0; nt < 2; nt++)
                        macc[mt][nt] = __builtin_amdgcn_mfma_f32_16x16x32_bf16(a[mt], bf[nt], macc[mt][nt], 0, 0, 0);
            }
        }
        __syncthreads();

        // ============ S5a: macc += u @ Wf, M=64 K=256 N=128 (no barrier after) ============
        {
            #pragma unroll
            for (int kb = 0; kb < 256; kb += 32) {
                v8s a[4], bf[2];
                #pragma unroll
                for (int mt = 0; mt < 4; mt++)
                    a[mt] = *reinterpret_cast<const v8s*>(&ubuf[(mt * 16 + l16) * US + kb + quad * 8]);
                #pragma unroll
                for (int nt = 0; nt < 2; nt++)
                    bf[nt] = *reinterpret_cast<const v8s*>(
                        &wfT[(size_t)(n * 128 + w * 32 + nt * 16 + l16) * 256 + kb + quad * 8]);
                #pragma unroll
                for (int mt = 0; mt < 4; mt++)
                    #pragma unroll
                    for (int nt = 0; nt < 2; nt++)
                        macc[mt][nt] = __builtin_amdgcn_mfma_f32_16x16x32_bf16(a[mt], bf[nt], macc[mt][nt], 0, 0, 0);
            }
        }
        // no barrier: next S1 writes hbuf (last read = S5b, behind the barrier
        // above); next S1/S2's zbuf & ubuf writes are 1-2 barriers ahead of
        // S5a's ubuf reads via the post-S1 and post-S2 barriers.
    }

    // ================= S7: m = gelu(macc + b1adj) -> zbuf (bf16) =================
    // (no barrier needed: zbuf's last readers [S3, band 6] are behind the
    //  post-S3 barrier; S5a touches only ubuf/wfT.)
    #pragma unroll
    for (int nt = 0; nt < 2; nt++) {
        const int col = w * 32 + nt * 16 + l16;
        const float bias = b2f(wsb[O_B1A + col]);
        #pragma unroll
        for (int mt = 0; mt < 4; mt++)
            #pragma unroll
            for (int r = 0; r < 4; r++)
                zbuf[(mt * 16 + quad * 4 + r) * HS + col] = f2b(gelu_exact(macc[mt][nt][r] + bias));
    }
    __syncthreads();

    // ================= S8: mix2, M=64 K=128 N=16 (wave w -> rows w*16..) =================
    {
        v4f acc = (v4f){0.f, 0.f, 0.f, 0.f};
        #pragma unroll
        for (int kb = 0; kb < 128; kb += 32) {
            v8s a  = *reinterpret_cast<const v8s*>(&zbuf[(w * 16 + l16) * HS + kb + quad * 8]);
            v8s bf = *reinterpret_cast<const v8s*>(&m2T[(size_t)l16 * 128 + kb + quad * 8]);
            acc = __builtin_amdgcn_mfma_f32_16x16x32_bf16(a, bf, acc, 0, 0, 0);
        }
        const float bias = mix_b2[l16];
        #pragma unroll
        for (int r = 0; r < 4; r++) {
            const int row = w * 16 + quad * 4 + r;
            out[((long)bb * TT + t0 + row) * SIN + l16] = acc[r] + bias;
        }
    }
}

// ---------------------------------------------------------------------------
extern "C" void kernel_launch(void* const* d_in, const int* in_sizes, int n_in,
                              void* d_out, int out_size, void* d_ws, size_t ws_size,
                              hipStream_t stream) {
    (void)in_sizes; (void)n_in; (void)out_size; (void)ws_size;
    const float* x      = (const float*)d_in[0];
    const float* conv_w = (const float*)d_in[1];
    const float* conv_b = (const float*)d_in[2];
    const float* dec_g  = (const float*)d_in[3];
    const float* dec_b  = (const float*)d_in[4];
    const float* n2_g   = (const float*)d_in[5];
    const float* n2_b   = (const float*)d_in[6];
    const float* ffn_w1 = (const float*)d_in[7];
    const float* ffn_b1 = (const float*)d_in[8];
    const float* ffn_w2 = (const float*)d_in[9];
    const float* ffn_b2 = (const float*)d_in[10];
    const float* proj_w = (const float*)d_in[11];
    const float* proj_b = (const float*)d_in[12];
    const float* mix_w1 = (const float*)d_in[13];
    const float* mix_b1 = (const float*)d_in[14];
    const float* mix_w2 = (const float*)d_in[15];
    const float* mix_b2 = (const float*)d_in[16];
    unsigned short* wsb = (unsigned short*)d_ws;
    float* out = (float*)d_out;

    hipLaunchKernelGGL(prep_weights, dim3(512), dim3(256), 0, stream,
                       conv_w, ffn_w1, proj_w, mix_w1, mix_w2, wsb);
    hipLaunchKernelGGL(prep_wf, dim3(512), dim3(256), 0, stream,
                       ffn_w2, ffn_b2, proj_b, mix_w1, mix_b1, wsb);
    hipLaunchKernelGGL(fused_main, dim3(BB * (TT / TM)), dim3(256), 0, stream,
                       x, conv_b, dec_g, dec_b, n2_g, n2_b, ffn_b1,
                       wsb, out, mix_b2);
}

// Round 10
// 446.062 us; speedup vs baseline: 1.3437x; 1.0042x over previous
//
#include <hip/hip_runtime.h>
#include <stdint.h>

// ---------------------------------------------------------------------------
// Problem constants
// ---------------------------------------------------------------------------
#define NB   7
#define SIN  16
#define DD   128
#define BB   32
#define TT   2048
#define TM   64          // t-rows per block
#define KMAX 31

// LDS strides (elements, ushort/bf16). All multiples of 8 (16B-aligned rows).
#define XWS  40          // x window stride  (95 rows)
#define HS   136         // h / z buffers (64 rows)
#define US   264         // u buffer (64 rows)

// ws (bf16 element offsets)
#define O_CWT 0           // [7][128][512]
#define O_W1T 458752      // [7][256][128]
#define O_WFT 688128      // [7][128][256]  Wf[n][c][e] = sum_d ffn_w2[n][e][d]*Wc[n][d][c]
#define O_WCT 917504      // [7][128][128]  Wc[n][c][k] = sum_j proj_w[n][k][j]*mix_w1[n*64+j][c]
#define O_M2T 1032192     // [16][128]
#define O_B1A 1034240     // [128] b1adj = mix_b1 + proj_b@mix_w1 + sum_n ffn_b2[n]@Wc[n]
#define W_TOTAL 1034368

// prep segment sizes
#define NSEG_CW  444416   // 7*31*16*128
#define NSEG_PAD 14336    // 7*128*16
#define NSEG_W1  229376   // 7*128*256
#define NSEG_WC  114688   // 7*128*128
#define NSEG_M2  2048
#define NSEG_WF  229376   // 7*256*128

typedef short v8s __attribute__((ext_vector_type(8)));
typedef float v4f __attribute__((ext_vector_type(4)));

__device__ __forceinline__ unsigned short f2b(float f) {
    unsigned u = __float_as_uint(f);
    u += 0x7fffu + ((u >> 16) & 1u);          // round-to-nearest-even
    return (unsigned short)(u >> 16);
}
__device__ __forceinline__ float b2f(unsigned short h) {
    return __uint_as_float(((unsigned)h) << 16);
}
// pack two f32 -> one u32 of 2x bf16 (RNE), single instruction on gfx950
__device__ __forceinline__ unsigned cvt_pk_bf16(float lo, float hi) {
    unsigned r;
    asm volatile("v_cvt_pk_bf16_f32 %0, %1, %2" : "=v"(r) : "v"(lo), "v"(hi));
    return r;
}
__device__ __forceinline__ float gelu_fast(float x) {   // sigmoid approx (inner FFN only)
    return x / (1.f + __expf(-1.702f * x));
}
__device__ __forceinline__ float gelu_exact(float x) {  // final mix gelu
    return 0.5f * x * (1.f + erff(x * 0.70710678118654752f));
}

// ---------------------------------------------------------------------------
// prep 1: fp32 -> bf16 transposed layouts + Wc = proj_w @ mix_w1.
// ---------------------------------------------------------------------------
__global__ void prep_weights(const float* __restrict__ conv_w,
                             const float* __restrict__ ffn_w1,
                             const float* __restrict__ proj_w,
                             const float* __restrict__ mix_w1,
                             const float* __restrict__ mix_w2,
                             unsigned short* __restrict__ wsb) {
    const int i0 = blockIdx.x * 256 + threadIdx.x;
    const int stride = gridDim.x * 256;

    // cwT[n][d][k*16+s] = conv_w[n][k][s][d]   (read coalesced over d)
    for (int o = i0; o < NSEG_CW; o += stride) {
        int n = o / 63488; int r = o % 63488;
        int k = r >> 11; int s = (r >> 7) & 15; int d = r & 127;
        float v = conv_w[((n * 31 + k) * 16 + s) * 128 + d];
        wsb[(size_t)(n * 128 + d) * 512 + k * 16 + s] = f2b(v);
    }
    // cwT zero pad (k == 31)
    for (int o = i0; o < NSEG_PAD; o += stride) {
        int n = o >> 11; int d = (o >> 4) & 127; int s = o & 15;
        wsb[(size_t)(n * 128 + d) * 512 + 496 + s] = 0;
    }
    // w1T[n][e][k] = ffn_w1[n][k][e]   (read coalesced over e)
    for (int o = i0; o < NSEG_W1; o += stride) {
        int n = o >> 15; int k = (o >> 8) & 127; int e = o & 255;
        float v = ffn_w1[(n * 128 + k) * 256 + e];
        wsb[O_W1T + (size_t)(n * 256 + e) * 128 + k] = f2b(v);
    }
    // WcT[n][c][k] = sum_j proj_w[n][k][j] * mix_w1[n*64+j][c]
    // (mix_w1 read coalesced over c; proj_w float4 wave-broadcast)
    for (int o = i0; o < NSEG_WC; o += stride) {
        int n = o >> 14; int k = (o >> 7) & 127; int c = o & 127;
        const float4* pw4 = (const float4*)(proj_w + (size_t)(n * 128 + k) * 64);
        const float* mw = mix_w1 + (size_t)(n * 64) * 128 + c;
        float s = 0.f;
        #pragma unroll 4
        for (int j4 = 0; j4 < 16; j4++) {
            float4 p = pw4[j4];
            const float* m = mw + (size_t)(j4 * 4) * 128;
            s += p.x * m[0] + p.y * m[128] + p.z * m[256] + p.w * m[384];
        }
        wsb[O_WCT + (size_t)(n * 128 + c) * 128 + k] = f2b(s);
    }
    // m2T[o16][c] = mix_w2[c][o16]
    for (int o = i0; o < NSEG_M2; o += stride) {
        int o16 = o >> 7; int c = o & 127;
        wsb[O_M2T + o16 * 128 + c] = f2b(mix_w2[c * 16 + o16]);
    }
}

// ---------------------------------------------------------------------------
// prep 2 (after prep_weights; same stream => ordered):
//   WfT[n][c][e] = sum_d ffn_w2[n][e][d] * Wc[n][d][c]
//   b1adj[c] = mix_b1[c] + proj_b@mix_w1 + sum_n ffn_b2[n]@Wc[n]
// R9 lesson (Common-mistake #2 on ourselves): the scalar bf16 inner loop cost
// ~45us. Vectorized: Wc rows via v8s (16B), ffn_w2 rows via float4 (wave-
// broadcast: the 128 consecutive o share e).
// ---------------------------------------------------------------------------
__global__ void prep_wf(const float* __restrict__ ffn_w2,
                        const float* __restrict__ ffn_b2,
                        const float* __restrict__ proj_b,
                        const float* __restrict__ mix_w1,
                        const float* __restrict__ mix_b1,
                        unsigned short* __restrict__ wsb) {
    const int i0 = blockIdx.x * 256 + threadIdx.x;
    const int stride = gridDim.x * 256;

    for (int o = i0; o < NSEG_WF; o += stride) {
        int n = o >> 15; int r = o & 32767;
        int e = r >> 7; int c = r & 127;
        const float4* w2v = (const float4*)(ffn_w2 + (size_t)(n * 256 + e) * 128);
        const v8s* wcv = (const v8s*)(wsb + O_WCT + (size_t)(n * 128 + c) * 128);
        float s = 0.f;
        #pragma unroll
        for (int d8 = 0; d8 < 16; d8++) {
            v8s h8 = wcv[d8];
            float4 a = w2v[d8 * 2], b = w2v[d8 * 2 + 1];
            s += a.x * b2f((unsigned short)h8[0]) + a.y * b2f((unsigned short)h8[1])
               + a.z * b2f((unsigned short)h8[2]) + a.w * b2f((unsigned short)h8[3])
               + b.x * b2f((unsigned short)h8[4]) + b.y * b2f((unsigned short)h8[5])
               + b.z * b2f((unsigned short)h8[6]) + b.w * b2f((unsigned short)h8[7]);
        }
        wsb[O_WFT + (size_t)(n * 128 + c) * 256 + e] = f2b(s);
    }
    for (int o = i0; o < 128; o += stride) {
        float s = mix_b1[o];
        #pragma unroll 8
        for (int kk = 0; kk < 448; kk++)
            s += proj_b[kk] * mix_w1[kk * 128 + o];
        for (int n = 0; n < NB; n++) {
            const v8s* wcv = (const v8s*)(wsb + O_WCT + (size_t)(n * 128 + o) * 128);
            const float4* fbv = (const float4*)(ffn_b2 + n * 128);
            #pragma unroll
            for (int d8 = 0; d8 < 16; d8++) {
                v8s h8 = wcv[d8];
                float4 a = fbv[d8 * 2], b = fbv[d8 * 2 + 1];
                s += a.x * b2f((unsigned short)h8[0]) + a.y * b2f((unsigned short)h8[1])
                   + a.z * b2f((unsigned short)h8[2]) + a.w * b2f((unsigned short)h8[3])
                   + b.x * b2f((unsigned short)h8[4]) + b.y * b2f((unsigned short)h8[5])
                   + b.z * b2f((unsigned short)h8[6]) + b.w * b2f((unsigned short)h8[7]);
            }
        }
        wsb[O_B1A + o] = f2b(s);
    }
}

// ---------------------------------------------------------------------------
// Fused main kernel (structure = round 9, verified): one block = 64 t-rows,
// 256 threads / 4 waves, 3 barrier-phases per band via the Wf/Wc algebra.
// This round: streaming in-place LN (S2) + v_cvt_pk_bf16_f32 epilogues.
// ---------------------------------------------------------------------------
__global__ __launch_bounds__(256, 2)
void fused_main(const float* __restrict__ x,
                const float* __restrict__ conv_b,
                const float* __restrict__ dec_g, const float* __restrict__ dec_b,
                const float* __restrict__ n2_g,  const float* __restrict__ n2_b,
                const float* __restrict__ ffn_b1,
                const unsigned short* __restrict__ wsb,
                float* __restrict__ out,
                const float* __restrict__ mix_b2) {
    __shared__ __align__(16) unsigned short xw[95 * XWS];    //  7,600 B
    __shared__ __align__(16) unsigned short hbuf[TM * HS];   // 17,408 B
    __shared__ __align__(16) unsigned short zbuf[TM * HS];   // 17,408 B
    __shared__ __align__(16) unsigned short ubuf[TM * US];   // 33,792 B

    const int tid  = threadIdx.x;
    const int lane = tid & 63;
    const int w    = tid >> 6;       // wave 0..3
    const int l16  = lane & 15;
    const int quad = lane >> 4;      // 0..3
    const int bb   = blockIdx.x >> 5;
    const int t0   = (blockIdx.x & 31) * TM;

    const unsigned short* cwT = wsb + O_CWT;
    const unsigned short* w1T = wsb + O_W1T;
    const unsigned short* wfT = wsb + O_WFT;
    const unsigned short* wcT = wsb + O_WCT;
    const unsigned short* m2T = wsb + O_M2T;

    // ---- S0: stage x window (rows t0-15 .. t0+78), bf16 ----
    for (int i = tid; i < 95 * SIN; i += 256) {
        int r = i >> 4, s = i & 15;
        int t = t0 + r - 15;
        float v = (t >= 0 && t < TT) ? x[((long)bb * TT + t) * SIN + s] : 0.f;
        xw[r * XWS + s] = f2b(v);
    }

    v4f macc[4][2];                  // persistent mix accumulators (cols w*32..w*32+31)
    #pragma unroll
    for (int a = 0; a < 4; a++)
        #pragma unroll
        for (int c = 0; c < 2; c++)
            macc[a][c] = (v4f){0.f, 0.f, 0.f, 0.f};

    __syncthreads();

    // per-band conv K-ranges (32-aligned, covering the non-zero taps)
    static const int lo_tab[NB] = {0, 64, 128, 160, 192, 192, 224};
    static const int hi_tab[NB] = {512, 416, 384, 352, 320, 288, 288};

    for (int n = 0; n < NB; ++n) {
        // ================= S1: conv (im2col GEMM), M=64 K=K~n N=128 =================
        {
            v4f acc[4][2];
            #pragma unroll
            for (int mt = 0; mt < 4; mt++)
                #pragma unroll
                for (int nt = 0; nt < 2; nt++) acc[mt][nt] = (v4f){0.f, 0.f, 0.f, 0.f};
            const int colb = w * 32;
            const int lo = lo_tab[n], hi = hi_tab[n];
            for (int kf = lo; kf < hi; kf += 32) {
                const int tap  = (kf >> 4) + (quad >> 1);
                const int scol = (quad & 1) * 8;
                v8s a[4], bf[2];
                #pragma unroll
                for (int mt = 0; mt < 4; mt++)
                    a[mt] = *reinterpret_cast<const v8s*>(&xw[(mt * 16 + l16 + tap) * XWS + scol]);
                #pragma unroll
                for (int nt = 0; nt < 2; nt++)
                    bf[nt] = *reinterpret_cast<const v8s*>(
                        &cwT[(size_t)(n * 128 + colb + nt * 16 + l16) * 512 + kf + quad * 8]);
                #pragma unroll
                for (int mt = 0; mt < 4; mt++)
                    #pragma unroll
                    for (int nt = 0; nt < 2; nt++)
                        acc[mt][nt] = __builtin_amdgcn_mfma_f32_16x16x32_bf16(a[mt], bf[nt], acc[mt][nt], 0, 0, 0);
            }
            #pragma unroll
            for (int nt = 0; nt < 2; nt++) {
                const int col = colb + nt * 16 + l16;
                const float bias = conv_b[n * 128 + col];
                #pragma unroll
                for (int mt = 0; mt < 4; mt++) {
                    unsigned p01 = cvt_pk_bf16(acc[mt][nt][0] + bias, acc[mt][nt][1] + bias);
                    unsigned p23 = cvt_pk_bf16(acc[mt][nt][2] + bias, acc[mt][nt][3] + bias);
                    const int r0 = (mt * 16 + quad * 4) * HS + col;
                    hbuf[r0]          = (unsigned short)p01;
                    hbuf[r0 + HS]     = (unsigned short)(p01 >> 16);
                    hbuf[r0 + 2 * HS] = (unsigned short)p23;
                    hbuf[r0 + 3 * HS] = (unsigned short)(p23 >> 16);
                }
            }
        }
        __syncthreads();

        // ======= S2: dual LayerNorm, streaming/in-place (4 lanes/row, 32 cols) =======
        {
            const int row = tid >> 2, q = tid & 3;
            const int base = row * HS + q * 32;
            v8s t8[4];
            #pragma unroll
            for (int c8 = 0; c8 < 4; c8++)
                t8[c8] = *reinterpret_cast<const v8s*>(&hbuf[base + c8 * 8]);
            float s1 = 0.f, s2 = 0.f;
            #pragma unroll
            for (int c8 = 0; c8 < 4; c8++)
                #pragma unroll
                for (int j = 0; j < 8; j++) {
                    float f = b2f((unsigned short)t8[c8][j]);
                    s1 += f; s2 = fmaf(f, f, s2);
                }
            s1 += __shfl_xor(s1, 1); s2 += __shfl_xor(s2, 1);
            s1 += __shfl_xor(s1, 2); s2 += __shfl_xor(s2, 2);
            const float m1 = s1 * (1.f / 128.f);
            const float rs = rsqrtf(s2 * (1.f / 128.f) - m1 * m1 + 1e-5f);
            const float m1rs = m1 * rs;
            const float4* dg4 = (const float4*)(dec_g + n * 128) + q * 8;
            const float4* db4 = (const float4*)(dec_b + n * 128) + q * 8;
            float t1 = 0.f, t2 = 0.f;
            unsigned hw[16];
            #pragma unroll
            for (int c4 = 0; c4 < 8; c4++) {
                float4 g4 = dg4[c4], b4 = db4[c4];
                float v0 = b2f((unsigned short)t8[c4 >> 1][(c4 & 1) * 4 + 0]);
                float v1 = b2f((unsigned short)t8[c4 >> 1][(c4 & 1) * 4 + 1]);
                float v2 = b2f((unsigned short)t8[c4 >> 1][(c4 & 1) * 4 + 2]);
                float v3 = b2f((unsigned short)t8[c4 >> 1][(c4 & 1) * 4 + 3]);
                float h0 = fmaf(fmaf(v0, rs, -m1rs), g4.x, b4.x);
                float h1 = fmaf(fmaf(v1, rs, -m1rs), g4.y, b4.y);
                float h2 = fmaf(fmaf(v2, rs, -m1rs), g4.z, b4.z);
                float h3 = fmaf(fmaf(v3, rs, -m1rs), g4.w, b4.w);
                t1 += h0 + h1 + h2 + h3;
                t2 = fmaf(h0, h0, t2); t2 = fmaf(h1, h1, t2);
                t2 = fmaf(h2, h2, t2); t2 = fmaf(h3, h3, t2);
                unsigned w01 = cvt_pk_bf16(h0, h1);
                unsigned w23 = cvt_pk_bf16(h2, h3);
                hw[c4 * 2] = w01; hw[c4 * 2 + 1] = w23;
                *reinterpret_cast<unsigned*>(&hbuf[base + c4 * 4])     = w01;
                *reinterpret_cast<unsigned*>(&hbuf[base + c4 * 4 + 2]) = w23;
            }
            t1 += __shfl_xor(t1, 1); t2 += __shfl_xor(t2, 1);
            t1 += __shfl_xor(t1, 2); t2 += __shfl_xor(t2, 2);
            const float m2 = t1 * (1.f / 128.f);
            const float rs2 = rsqrtf(t2 * (1.f / 128.f) - m2 * m2 + 1e-5f);
            const float m2rs2 = m2 * rs2;
            const float4* ng4 = (const float4*)(n2_g + n * 128) + q * 8;
            const float4* nb4 = (const float4*)(n2_b + n * 128) + q * 8;
            #pragma unroll
            for (int c4 = 0; c4 < 8; c4++) {
                float4 g4 = ng4[c4], b4 = nb4[c4];
                unsigned w01 = hw[c4 * 2], w23 = hw[c4 * 2 + 1];
                float h0 = __uint_as_float(w01 << 16);
                float h1 = __uint_as_float(w01 & 0xffff0000u);
                float h2 = __uint_as_float(w23 << 16);
                float h3 = __uint_as_float(w23 & 0xffff0000u);
                float z0 = fmaf(fmaf(h0, rs2, -m2rs2), g4.x, b4.x);
                float z1 = fmaf(fmaf(h1, rs2, -m2rs2), g4.y, b4.y);
                float z2 = fmaf(fmaf(h2, rs2, -m2rs2), g4.z, b4.z);
                float z3 = fmaf(fmaf(h3, rs2, -m2rs2), g4.w, b4.w);
                *reinterpret_cast<unsigned*>(&zbuf[base + c4 * 4])     = cvt_pk_bf16(z0, z1);
                *reinterpret_cast<unsigned*>(&zbuf[base + c4 * 4 + 2]) = cvt_pk_bf16(z2, z3);
            }
        }
        __syncthreads();

        // ========== S3: FFN1 + gelu (zbuf -> ubuf)  +  S5b: macc += h @ Wc ==========
        {
            v4f acc[4][4];
            #pragma unroll
            for (int mt = 0; mt < 4; mt++)
                #pragma unroll
                for (int et = 0; et < 4; et++) acc[mt][et] = (v4f){0.f, 0.f, 0.f, 0.f};
            const int eb = w * 64;
            #pragma unroll
            for (int kb = 0; kb < 128; kb += 32) {
                v8s a[4], bf[4];
                #pragma unroll
                for (int mt = 0; mt < 4; mt++)
                    a[mt] = *reinterpret_cast<const v8s*>(&zbuf[(mt * 16 + l16) * HS + kb + quad * 8]);
                #pragma unroll
                for (int et = 0; et < 4; et++)
                    bf[et] = *reinterpret_cast<const v8s*>(
                        &w1T[(size_t)(n * 256 + eb + et * 16 + l16) * 128 + kb + quad * 8]);
                #pragma unroll
                for (int mt = 0; mt < 4; mt++)
                    #pragma unroll
                    for (int et = 0; et < 4; et++)
                        acc[mt][et] = __builtin_amdgcn_mfma_f32_16x16x32_bf16(a[mt], bf[et], acc[mt][et], 0, 0, 0);
            }
            #pragma unroll
            for (int et = 0; et < 4; et++) {
                const int e = eb + et * 16 + l16;
                const float bias = ffn_b1[n * 256 + e];
                #pragma unroll
                for (int mt = 0; mt < 4; mt++) {
                    float g0 = gelu_fast(acc[mt][et][0] + bias);
                    float g1 = gelu_fast(acc[mt][et][1] + bias);
                    float g2 = gelu_fast(acc[mt][et][2] + bias);
                    float g3 = gelu_fast(acc[mt][et][3] + bias);
                    unsigned p01 = cvt_pk_bf16(g0, g1);
                    unsigned p23 = cvt_pk_bf16(g2, g3);
                    const int r0 = (mt * 16 + quad * 4) * US + e;
                    ubuf[r0]          = (unsigned short)p01;
                    ubuf[r0 + US]     = (unsigned short)(p01 >> 16);
                    ubuf[r0 + 2 * US] = (unsigned short)p23;
                    ubuf[r0 + 3 * US] = (unsigned short)(p23 >> 16);
                }
            }
            // S5b: macc += h @ Wc   (hbuf is final LN1 output; zbuf/ubuf untouched)
            #pragma unroll
            for (int kb = 0; kb < 128; kb += 32) {
                v8s a[4], bf[2];
                #pragma unroll
                for (int mt = 0; mt < 4; mt++)
                    a[mt] = *reinterpret_cast<const v8s*>(&hbuf[(mt * 16 + l16) * HS + kb + quad * 8]);
                #pragma unroll
                for (int nt = 0; nt < 2; nt++)
                    bf[nt] = *reinterpret_cast<const v8s*>(
                        &wcT[(size_t)(n * 128 + w * 32 + nt * 16 + l16) * 128 + kb + quad * 8]);
                #pragma unroll
                for (int mt = 0; mt < 4; mt++)
                    #pragma unroll
                    for (int nt = 0; nt < 2; nt++)
                        macc[mt][nt] = __builtin_amdgcn_mfma_f32_16x16x32_bf16(a[mt], bf[nt], macc[mt][nt], 0, 0, 0);
            }
        }
        __syncthreads();

        // ============ S5a: macc += u @ Wf, M=64 K=256 N=128 (no barrier after) ============
        {
            #pragma unroll
            for (int kb = 0; kb < 256; kb += 32) {
                v8s a[4], bf[2];
                #pragma unroll
                for (int mt = 0; mt < 4; mt++)
                    a[mt] = *reinterpret_cast<const v8s*>(&ubuf[(mt * 16 + l16) * US + kb + quad * 8]);
                #pragma unroll
                for (int nt = 0; nt < 2; nt++)
                    bf[nt] = *reinterpret_cast<const v8s*>(
                        &wfT[(size_t)(n * 128 + w * 32 + nt * 16 + l16) * 256 + kb + quad * 8]);
                #pragma unroll
                for (int mt = 0; mt < 4; mt++)
                    #pragma unroll
                    for (int nt = 0; nt < 2; nt++)
                        macc[mt][nt] = __builtin_amdgcn_mfma_f32_16x16x32_bf16(a[mt], bf[nt], macc[mt][nt], 0, 0, 0);
            }
        }
        // no barrier: next S1 writes hbuf (last read = S5b, behind the barrier
        // above); next S1/S2's zbuf & ubuf writes are 1-2 barriers ahead of
        // S5a's ubuf reads via the post-S1 and post-S2 barriers.
    }

    // ================= S7: m = gelu(macc + b1adj) -> zbuf (bf16) =================
    // (no barrier needed: zbuf's last readers [S3, band 6] are behind the
    //  post-S3 barrier; S5a touches only ubuf/wfT.)
    #pragma unroll
    for (int nt = 0; nt < 2; nt++) {
        const int col = w * 32 + nt * 16 + l16;
        const float bias = b2f(wsb[O_B1A + col]);
        #pragma unroll
        for (int mt = 0; mt < 4; mt++) {
            float g0 = gelu_exact(macc[mt][nt][0] + bias);
            float g1 = gelu_exact(macc[mt][nt][1] + bias);
            float g2 = gelu_exact(macc[mt][nt][2] + bias);
            float g3 = gelu_exact(macc[mt][nt][3] + bias);
            unsigned p01 = cvt_pk_bf16(g0, g1);
            unsigned p23 = cvt_pk_bf16(g2, g3);
            const int r0 = (mt * 16 + quad * 4) * HS + col;
            zbuf[r0]          = (unsigned short)p01;
            zbuf[r0 + HS]     = (unsigned short)(p01 >> 16);
            zbuf[r0 + 2 * HS] = (unsigned short)p23;
            zbuf[r0 + 3 * HS] = (unsigned short)(p23 >> 16);
        }
    }
    __syncthreads();

    // ================= S8: mix2, M=64 K=128 N=16 (wave w -> rows w*16..) =================
    {
        v4f acc = (v4f){0.f, 0.f, 0.f, 0.f};
        #pragma unroll
        for (int kb = 0; kb < 128; kb += 32) {
            v8s a  = *reinterpret_cast<const v8s*>(&zbuf[(w * 16 + l16) * HS + kb + quad * 8]);
            v8s bf = *reinterpret_cast<const v8s*>(&m2T[(size_t)l16 * 128 + kb + quad * 8]);
            acc = __builtin_amdgcn_mfma_f32_16x16x32_bf16(a, bf, acc, 0, 0, 0);
        }
        const float bias = mix_b2[l16];
        #pragma unroll
        for (int r = 0; r < 4; r++) {
            const int row = w * 16 + quad * 4 + r;
            out[((long)bb * TT + t0 + row) * SIN + l16] = acc[r] + bias;
        }
    }
}

// ---------------------------------------------------------------------------
extern "C" void kernel_launch(void* const* d_in, const int* in_sizes, int n_in,
                              void* d_out, int out_size, void* d_ws, size_t ws_size,
                              hipStream_t stream) {
    (void)in_sizes; (void)n_in; (void)out_size; (void)ws_size;
    const float* x      = (const float*)d_in[0];
    const float* conv_w = (const float*)d_in[1];
    const float* conv_b = (const float*)d_in[2];
    const float* dec_g  = (const float*)d_in[3];
    const float* dec_b  = (const float*)d_in[4];
    const float* n2_g   = (const float*)d_in[5];
    const float* n2_b   = (const float*)d_in[6];
    const float* ffn_w1 = (const float*)d_in[7];
    const float* ffn_b1 = (const float*)d_in[8];
    const float* ffn_w2 = (const float*)d_in[9];
    const float* ffn_b2 = (const float*)d_in[10];
    const float* proj_w = (const float*)d_in[11];
    const float* proj_b = (const float*)d_in[12];
    const float* mix_w1 = (const float*)d_in[13];
    const float* mix_b1 = (const float*)d_in[14];
    const float* mix_w2 = (const float*)d_in[15];
    const float* mix_b2 = (const float*)d_in[16];
    unsigned short* wsb = (unsigned short*)d_ws;
    float* out = (float*)d_out;

    hipLaunchKernelGGL(prep_weights, dim3(512), dim3(256), 0, stream,
                       conv_w, ffn_w1, proj_w, mix_w1, mix_w2, wsb);
    hipLaunchKernelGGL(prep_wf, dim3(512), dim3(256), 0, stream,
                       ffn_w2, ffn_b2, proj_b, mix_w1, mix_b1, wsb);
    hipLaunchKernelGGL(fused_main, dim3(BB * (TT / TM)), dim3(256), 0, stream,
                       x, conv_b, dec_g, dec_b, n2_g, n2_b, ffn_b1,
                       wsb, out, mix_b2);
}